// Round 14
// baseline (249.035 us; speedup 1.0000x reference)
//
#include <hip/hip_runtime.h>

#define Bb 2
#define Tt 2048
#define Dd 1024
#define Hh 16
#define LDC 4480

typedef __attribute__((ext_vector_type(8))) short s16x8;
typedef __attribute__((ext_vector_type(4))) float f32x4;
typedef __attribute__((ext_vector_type(8))) _Float16 f16x8;

__device__ __forceinline__ float bf2f(unsigned short u) {
  unsigned v = ((unsigned)u) << 16;
  union { unsigned u; float f; } c; c.u = v; return c.f;
}
__device__ __forceinline__ unsigned short f2bf(float f) {
  union { float f; unsigned u; } c; c.f = f;
  unsigned u = c.u + 0x7fffu + ((c.u >> 16) & 1u);
  return (unsigned short)(u >> 16);
}
__device__ __forceinline__ float sigm(float x) { return 1.f / (1.f + expf(-x)); }

// global -> LDS direct DMA, 16B per lane: lane i's 16B land at ldsbase + i*16.
typedef const __attribute__((address_space(1))) void* gas_ptr;
typedef __attribute__((address_space(3))) void* las_ptr;
__device__ __forceinline__ void gload_lds16(const unsigned short* g, unsigned short* l) {
  __builtin_amdgcn_global_load_lds((gas_ptr)g, (las_ptr)l, 16, 0, 0);
}

// Fragment-major operand layout: frag(t16, kt) holds 64 lanes x 16 B where
// lane = (row&15) + quad*16, bytes = elems [kt*32 + quad*8 .. +8) of row.

// ---------------- fused prep: cast x + build WT + transpose out_w + bias ------
// WT/outT blocks each process 4 kt to amortize per-block staging overhead.
// Grid: 2048 + 1120 + 256 + 18 = 3442.

__global__ __launch_bounds__(256) void prep_kernel(const float* __restrict__ x,
                                                   const float* __restrict__ qkv_w,
                                                   const float* __restrict__ w1w,
                                                   const float* __restrict__ w2w,
                                                   const float* __restrict__ w1r,
                                                   const float* __restrict__ w2r,
                                                   const float* __restrict__ memg_w,
                                                   const float* __restrict__ memv_w,
                                                   const float* __restrict__ out_w,
                                                   const float* __restrict__ qkv_b,
                                                   const float* __restrict__ memg_b,
                                                   const float* __restrict__ memv_b,
                                                   unsigned short* __restrict__ xb,
                                                   unsigned short* __restrict__ WT,
                                                   unsigned short* __restrict__ outT,
                                                   float* __restrict__ biasC) {
  __shared__ float tile[32][33];
  int id = blockIdx.x;
  if (id < 2048) {
    // cast x -> A-fragment-major bf16
    int i = id * 256 + threadIdx.x;     // 16B chunk index
    int row = i >> 7;
    int k8 = i & 127;                    // 8-elem group
    const float4* xv = reinterpret_cast<const float4*>(x + (size_t)i * 8);
    float4 a = xv[0], b = xv[1];
    s16x8 out;
    out[0] = (short)f2bf(a.x); out[1] = (short)f2bf(a.y);
    out[2] = (short)f2bf(a.z); out[3] = (short)f2bf(a.w);
    out[4] = (short)f2bf(b.x); out[5] = (short)f2bf(b.y);
    out[6] = (short)f2bf(b.z); out[7] = (short)f2bf(b.w);
    int mt = row >> 4, kt = k8 >> 2, quad = k8 & 3;
    int lane = (row & 15) + quad * 16;
    *(s16x8*)&xb[(((size_t)mt * 32 + kt) * 64 + lane) * 8] = out;
  } else if (id < 3168) {
    // build WT (concat) -> B-fragment-major; 4 kt per block
    int j = id - 2048;                  // 0..1119
    int n0 = (j % 140) * 32, kt0 = (j / 140) * 4;
    int tx = threadIdx.x & 31, ty = threadIdx.x >> 5;
    for (int kk = 0; kk < 4; kk++) {
      int kt = kt0 + kk, k0 = kt * 32;
#pragma unroll
      for (int i = 0; i < 4; i++) {
        int k = k0 + ty + i * 8, n = n0 + tx;
        float v;
        if (n < 3072)       v = qkv_w[(size_t)k * 3072 + n];
        else if (n < 3136)  v = w1w[k * 64 + (n - 3072)];
        else if (n < 3200)  v = w2w[k * 64 + (n - 3136)];
        else if (n < 3264)  v = w1r[k * 64 + (n - 3200)];
        else if (n < 3328)  v = w2r[k * 64 + (n - 3264)];
        else if (n < 3344)  v = memg_w[k * 16 + (n - 3328)];
        else if (n < 3392)  v = 0.f;
        else if (n < 4416)  v = memv_w[(size_t)k * 1024 + (n - 3392)];
        else                v = 0.f;
        tile[ty + i * 8][tx] = v;
      }
      __syncthreads();
      if (threadIdx.x < 128) {
        int nl = threadIdx.x & 31, quad = threadIdx.x >> 5;
        s16x8 out;
#pragma unroll
        for (int e = 0; e < 8; e++) out[e] = (short)f2bf(tile[quad * 8 + e][nl]);
        int nt = (n0 >> 4) + (nl >> 4);
        int lane = (nl & 15) + quad * 16;
        *(s16x8*)&WT[(((size_t)nt * 32 + kt) * 64 + lane) * 8] = out;
      }
      __syncthreads();   // tile readers done before next kk overwrites
    }
  } else if (id < 3424) {
    // transpose out_w -> B-fragment-major outT; 4 kt per block
    int j = id - 3168;                  // 0..255
    int n0 = (j & 31) * 32, kt0 = (j >> 5) * 4;
    int tx = threadIdx.x & 31, ty = threadIdx.x >> 5;
    for (int kk = 0; kk < 4; kk++) {
      int kt = kt0 + kk, k0 = kt * 32;
#pragma unroll
      for (int i = 0; i < 4; i++) {
        int k = k0 + ty + i * 8, n = n0 + tx;
        tile[ty + i * 8][tx] = out_w[(size_t)k * 1024 + n];
      }
      __syncthreads();
      if (threadIdx.x < 128) {
        int nl = threadIdx.x & 31, quad = threadIdx.x >> 5;
        s16x8 out;
#pragma unroll
        for (int e = 0; e < 8; e++) out[e] = (short)f2bf(tile[quad * 8 + e][nl]);
        int nt = (n0 >> 4) + (nl >> 4);
        int lane = (nl & 15) + quad * 16;
        *(s16x8*)&outT[(((size_t)nt * 32 + kt) * 64 + lane) * 8] = out;
      }
      __syncthreads();
    }
  } else {
    int i = (id - 3424) * 256 + threadIdx.x;
    if (i < LDC) {
      float v = 0.f;
      if (i < 3072) v = qkv_b[i];
      else if (i >= 3328 && i < 3344) v = memg_b[i - 3328];
      else if (i >= 3392 && i < 4416) v = memv_b[i - 3392];
      biasC[i] = v;
    }
  }
}

// ---------------- wide-block LDS-staged fragment MFMA GEMM -------------------
// 256x128 block tile, 8 waves (512 thr), each wave the PROVEN shape: 4x4 acc,
// 8 ds_read_b128, 16 MFMA, 3 gload_lds per K-step; same 2-barrier structure
// as the measured 55.1 us 128x128 kernel. Block intensity 44 FLOP/B (was 33):
// A frags feed 2 waves, B frags 4. LDS 48 KB -> 3 blocks/CU (24 waves/CU).
// Grid 576 = 8 XCDs x (8 mTiles x 9 nTile-slots); nTile>=35 slots return.

__global__ __launch_bounds__(512) void gemm_wide_kernel(const unsigned short* __restrict__ Af,
                                                        const unsigned short* __restrict__ Bf,
                                                        unsigned short* __restrict__ Cout,
                                                        const float* __restrict__ bias) {
  __shared__ __align__(16) unsigned short lds[2][24][512];  // 2 buf x 24 frags = 48KB
  const int xx = blockIdx.x & 7, local = blockIdx.x >> 3;   // local 0..71
  const int mTile = (xx >> 2) * 8 + (local & 7);            // 0..15 (256-row tiles)
  const int nTile = (xx & 3) * 9 + (local >> 3);            // 0..35 (128-col tiles)
  if (nTile >= 35) return;   // uniform whole-block return, before any barrier
  const int lane = threadIdx.x & 63, wid = threadIdx.x >> 6;
  const int quad = lane >> 4, c16 = lane & 15;
  const int wm = wid >> 1, wn = wid & 1;   // 4x2 wave grid; wave tile 64x64
  const int mt0 = mTile * 16 + wm * 4;     // global 16-row frag index
  const int nt0 = nTile * 8 + wn * 4;      // global 16-col frag index

  // wave stages frags f = wid*3 .. wid*3+2 (f<16: A frag, else B frag f-16)
  const unsigned short* src[3];
#pragma unroll
  for (int i = 0; i < 3; i++) {
    int f = wid * 3 + i;
    src[i] = ((f < 16) ? (Af + (size_t)(mTile * 16 + f) * 16384)
                       : (Bf + (size_t)(nTile * 8 + (f - 16)) * 16384))
             + (size_t)lane * 8;
  }

  f32x4 acc[4][4] = {};

#pragma unroll
  for (int i = 0; i < 3; i++) gload_lds16(src[i], &lds[0][wid * 3 + i][0]);
  __syncthreads();

  int buf = 0;
  for (int kt = 0; kt < 32; kt++) {
    if (kt + 1 < 32) {
#pragma unroll
      for (int i = 0; i < 3; i++)
        gload_lds16(src[i] + (size_t)(kt + 1) * 512, &lds[buf ^ 1][wid * 3 + i][0]);
    }
    s16x8 a[4], b[4];
#pragma unroll
    for (int i = 0; i < 4; i++) {
      a[i] = *(const s16x8*)&lds[buf][wm * 4 + i][lane * 8];
      b[i] = *(const s16x8*)&lds[buf][16 + wn * 4 + i][lane * 8];
    }
#pragma unroll
    for (int mt = 0; mt < 4; mt++)
#pragma unroll
      for (int nt = 0; nt < 4; nt++)
        acc[mt][nt] = __builtin_amdgcn_mfma_f32_16x16x32_bf16(a[mt], b[nt],
                                                              acc[mt][nt], 0, 0, 0);
    __syncthreads();
    buf ^= 1;
  }

#pragma unroll
  for (int mt = 0; mt < 4; mt++)
#pragma unroll
    for (int nt = 0; nt < 4; nt++) {
      int col = (nt0 + nt) * 16 + c16;
      float bv = bias[col];
#pragma unroll
      for (int r = 0; r < 4; r++) {
        int row = (mt0 + mt) * 16 + quad * 4 + r;
        Cout[(size_t)row * 4480 + col] = f2bf(acc[mt][nt][r] + bv);
      }
    }
}

// ---------------- output GEMM: 4096x1024 fp32, 128x64 tiles, 512 blocks ------

__global__ __launch_bounds__(256) void gemm_out_kernel(const unsigned short* __restrict__ Af,
                                                       const unsigned short* __restrict__ Bf,
                                                       float* __restrict__ Cout,
                                                       const float* __restrict__ bias) {
  __shared__ __align__(16) unsigned short lds[2][12][512];  // 24 KB
  const int mTile = blockIdx.x >> 4;    // 0..31
  const int nTile = blockIdx.x & 15;    // 0..15
  const int lane = threadIdx.x & 63, wid = threadIdx.x >> 6;
  const int quad = lane >> 4, c16 = lane & 15;
  const int wm = wid >> 1, wn = wid & 1;
  const int mt0 = mTile * 8 + wm * 4;   // 16-row frag index
  const int nt0 = nTile * 4 + wn * 2;   // 16-col frag index

  // 12 frags (8 A + 4 B); wave stages f = wid*3 .. wid*3+2
  const unsigned short* src[3];
#pragma unroll
  for (int i = 0; i < 3; i++) {
    int f = wid * 3 + i;
    src[i] = ((f < 8) ? (Af + (size_t)(mTile * 8 + f) * 16384)
                      : (Bf + (size_t)(nTile * 4 + (f - 8)) * 16384))
             + (size_t)lane * 8;
  }

  f32x4 acc[4][2] = {};

#pragma unroll
  for (int i = 0; i < 3; i++) gload_lds16(src[i], &lds[0][wid * 3 + i][0]);
  __syncthreads();

  int buf = 0;
  for (int kt = 0; kt < 32; kt++) {
    if (kt + 1 < 32) {
#pragma unroll
      for (int i = 0; i < 3; i++)
        gload_lds16(src[i] + (size_t)(kt + 1) * 512, &lds[buf ^ 1][wid * 3 + i][0]);
    }
    s16x8 a[4], b[2];
#pragma unroll
    for (int i = 0; i < 4; i++)
      a[i] = *(const s16x8*)&lds[buf][wm * 4 + i][lane * 8];
#pragma unroll
    for (int j = 0; j < 2; j++)
      b[j] = *(const s16x8*)&lds[buf][8 + wn * 2 + j][lane * 8];
#pragma unroll
    for (int i = 0; i < 4; i++)
#pragma unroll
      for (int j = 0; j < 2; j++)
        acc[i][j] = __builtin_amdgcn_mfma_f32_16x16x32_bf16(a[i], b[j],
                                                            acc[i][j], 0, 0, 0);
    __syncthreads();
    buf ^= 1;
  }

#pragma unroll
  for (int i = 0; i < 4; i++)
#pragma unroll
    for (int j = 0; j < 2; j++) {
      int col = (nt0 + j) * 16 + c16;
      float bv = bias[col];
#pragma unroll
      for (int r = 0; r < 4; r++) {
        int row = (mt0 + i) * 16 + quad * 4 + r;
        Cout[(size_t)row * 1024 + col] = acc[i][j][r] + bv;
      }
    }
}

// ---------------- Plucker helper ----------------

__device__ __forceinline__ void ext6(const float* p, const float* q, float* L) {
  L[0] = p[0] * q[1] - p[1] * q[0];
  L[1] = p[0] * q[2] - p[2] * q[0];
  L[2] = p[0] * q[3] - p[3] * q[0];
  L[3] = p[1] * q[2] - p[2] * q[1];
  L[4] = p[1] * q[3] - p[3] * q[1];
  L[5] = p[2] * q[3] - p[3] * q[2];
  float n = sqrtf(L[0]*L[0] + L[1]*L[1] + L[2]*L[2] + L[3]*L[3] + L[4]*L[4] + L[5]*L[5]);
  float inv = 1.f / fmaxf(n, 1e-12f);
#pragma unroll
  for (int k = 0; k < 6; k++) L[k] *= inv;
}

// ---------------- post1: repack K/V tiles (blocks<2048) + lines (rest) --------
// K is pre-scaled by 0.125 (= DH^-0.5, a power of two, so scores are
// bit-identical to post-scaling) so attn's softmax path skips the multiply.

__global__ __launch_bounds__(256) void post1_kernel(const unsigned short* __restrict__ Cq,
                                                    unsigned short* __restrict__ Kt,
                                                    unsigned short* __restrict__ Vt,
                                                    float* __restrict__ Jw,
                                                    float* __restrict__ Jr,
                                                    float* __restrict__ rd) {
  __shared__ unsigned short vt[32 * 66];
  int id = blockIdx.x;
  int tid = threadIdx.x;
  if (id < 2048) {
    int kb = id & 63, bh = id >> 6;
    int b = bh >> 4, h = bh & 15;
    size_t tbase = ((size_t)bh * 64 + kb) * 2048;
    {
      int key = tid >> 3, p = tid & 7, dg = p ^ (key & 7);
      size_t src = (size_t)(b * Tt + kb * 32 + key) * LDC + 1024 + h * 64 + dg * 8;
      s16x8 kv = *(const s16x8*)&Cq[src];
      s16x8 kvs;
#pragma unroll
      for (int e = 0; e < 8; e++)
        kvs[e] = (short)f2bf(bf2f((unsigned short)kv[e]) * 0.125f);
      *(s16x8*)&Kt[tbase + (size_t)tid * 8] = kvs;
    }
    {
      int row = tid >> 3, c = tid & 7;
      size_t src = (size_t)(b * Tt + kb * 32 + row) * LDC + 2048 + h * 64 + c * 8;
      s16x8 vv = *(const s16x8*)&Cq[src];
#pragma unroll
      for (int e = 0; e < 8; e++) {
        union { _Float16 hf; unsigned short s; } cv;
        cv.hf = (_Float16)bf2f((unsigned short)vv[e]);
        vt[row * 66 + c * 8 + e] = cv.s;
      }
    }
    __syncthreads();
    {
      int d = tid >> 2, p = tid & 3, cq = p ^ ((d >> 2) & 3);
      s16x8 out;
#pragma unroll
      for (int e = 0; e < 8; e++) {
        int key = ((e >> 2) & 1) * 16 + cq * 4 + (e & 3);
        out[e] = (short)vt[key * 66 + d];
      }
      *(s16x8*)&Vt[tbase + (size_t)tid * 8] = out;
    }
  } else {
    int idx = (id - 2048) * 256 + tid;
    int h = idx & 15, t = (idx >> 4) & 2047, b = idx >> 15;
    size_t row = (size_t)(b * Tt + t) * LDC;
    float w1[4], w2[4], r1[4], r2[4];
#pragma unroll
    for (int k = 0; k < 4; k++) {
      w1[k] = (t > 0) ? bf2f(Cq[row - LDC + 3072 + h * 4 + k]) : 0.f;
      w2[k] = bf2f(Cq[row + 3136 + h * 4 + k]);
      r1[k] = bf2f(Cq[row + 3200 + h * 4 + k]);
      r2[k] = bf2f(Cq[row + 3264 + h * 4 + k]);
    }
    float Lw[6], Lr[6];
    ext6(w1, w2, Lw);
    ext6(r1, r2, Lr);
    size_t ob = ((size_t)(b * Hh + h) * Tt + t) * 6;
    Jw[ob + 0] = Lw[5]; Jw[ob + 1] = -Lw[4]; Jw[ob + 2] = Lw[3];
    Jw[ob + 3] = Lw[2]; Jw[ob + 4] = -Lw[1]; Jw[ob + 5] = Lw[0];
    Jr[ob + 0] = Lr[5]; Jr[ob + 1] = -Lr[4]; Jr[ob + 2] = Lr[3];
    Jr[ob + 3] = Lr[2]; Jr[ob + 4] = -Lr[1]; Jr[ob + 5] = Lr[0];
#pragma unroll
    for (int k = 0; k < 6; k++) rd[ob + k] = Lr[k];
  }
}

// ---------------- merged launch: fat-wave attn (blocks 0..1023) + scanA -------
// attn and scanA have no mutual dependency (both read only post1 outputs;
// attn writes po, scanA writes chunkA). One launch saves scanA's serial time
// (its tiny blocks backfill SIMD slots under attn) plus one dispatch gap.

__device__ __forceinline__ void do_tile(int ks, int q0, int quad, int c16,
                                        const s16x8& qf0, const s16x8& qf1,
                                        const s16x8 kf[2][2], const f16x8 vb[4],
                                        float& l_i, f32x4 o[4]) {
  f32x4 st0 = {}, st1 = {};
  __builtin_amdgcn_s_setprio(1);
  st0 = __builtin_amdgcn_mfma_f32_16x16x32_bf16(kf[0][0], qf0, st0, 0, 0, 0);
  st0 = __builtin_amdgcn_mfma_f32_16x16x32_bf16(kf[0][1], qf1, st0, 0, 0, 0);
  st1 = __builtin_amdgcn_mfma_f32_16x16x32_bf16(kf[1][0], qf0, st1, 0, 0, 0);
  st1 = __builtin_amdgcn_mfma_f32_16x16x32_bf16(kf[1][1], qf1, st1, 0, 0, 0);
  __builtin_amdgcn_s_setprio(0);
  bool need_mask = (ks + 31 > q0);
  f16x8 pa;
  float lp = 0.f;
#pragma unroll
  for (int r = 0; r < 4; r++) {
    float v0 = st0[r];     // K pre-scaled by 0.125 in post1
    float v1 = st1[r];
    if (need_mask) {
      v0 = (ks + quad * 4 + r      <= q0 + c16) ? v0 : -1e30f;
      v1 = (ks + 16 + quad * 4 + r <= q0 + c16) ? v1 : -1e30f;
    }
    float p0 = __expf(v0);
    float p1 = __expf(v1);
    lp += p0 + p1;
    pa[r]     = (_Float16)p0;
    pa[4 + r] = (_Float16)p1;
  }
  l_i += lp;
  __builtin_amdgcn_s_setprio(1);
#pragma unroll
  for (int nt = 0; nt < 4; nt++)
    o[nt] = __builtin_amdgcn_mfma_f32_16x16x32_f16(pa, vb[nt], o[nt], 0, 0, 0);
  __builtin_amdgcn_s_setprio(0);
}

__global__ __launch_bounds__(128, 2) void attn_scanA_kernel(const unsigned short* __restrict__ Cq,
                                                            const unsigned short* __restrict__ Kt,
                                                            const unsigned short* __restrict__ Vt,
                                                            unsigned short* __restrict__ po,
                                                            const float* __restrict__ Jw,
                                                            const float* __restrict__ Jr,
                                                            const float* __restrict__ decay_logits,
                                                            float* __restrict__ chunkA) {
  __shared__ float mrg[64][69];   // attn merge buffer
  __shared__ float sv[768];       // scanA staging
  if (blockIdx.x >= 1024) {
    // ---- scanA path (blocks 1024..2047) ----
    int blk = blockIdx.x - 1024;
    int chunk = blk & 15, bh = (blk >> 4) & 31, type = blk >> 9;
    int tid = threadIdx.x;
    const float* V = (type == 0 ? Jw : Jr) + ((size_t)bh * Tt + chunk * 128) * 6;
    for (int i = tid; i < 768; i += 128) sv[i] = V[i];
    __syncthreads();
    float d = sigm(decay_logits[bh & 15]);
    if (tid < 36) {
      int i6 = tid / 6, j6 = tid % 6;
      float A = 0.f;
      for (int s = 0; s < 128; s++) A = d * A + sv[s * 6 + i6] * sv[s * 6 + j6];
      chunkA[((size_t)(type * 32 + bh) * 16 + chunk) * 36 + tid] = A;
    }
    return;
  }
  // ---- attn path (blocks 0..1023) — verified round-12 code ----
  const int id = blockIdx.x;
  const int xcd = id & 7, rest = id >> 3;       // rest 0..127
  const int j = rest & 31;                      // strip-pair 0..31
  const int bh = ((rest >> 5) << 3) | xcd;      // 0..31
  const int b = bh >> 4, h = bh & 15;
  const int kw = threadIdx.x >> 6, lane = threadIdx.x & 63;
  const int quad = lane >> 4, c16 = lane & 15;
  const int qA0r = j * 32,        qA1r = j * 32 + 16;
  const int qB0r = 2016 - j * 32, qB1r = 2032 - j * 32;
  const int Ttot = 64 - j;                      // K-tiles needed (B strips)
  const int ht = (j >= 16) ? 16 : (32 - j);     // balanced split: 64/66 do_tiles
  const int t0 = kw ? ht : 0;
  const int t1 = kw ? Ttot : ht;
  const char* Kbase = (const char*)(Kt + (size_t)bh * 64 * 2048);
  const char* Vbase = (const char*)(Vt + (size_t)bh * 64 * 2048);
  const int vK0 = c16 * 128 + ((quad       ^ (c16 & 7)) * 16);
  const int vK1 = c16 * 128 + (((4 + quad) ^ (c16 & 7)) * 16);
  const int vV  = c16 * 64  + ((quad ^ ((c16 >> 2) & 3)) * 16);

  size_t rowA0 = (size_t)(b * Tt + qA0r + c16) * LDC + h * 64;
  size_t rowA1 = (size_t)(b * Tt + qA1r + c16) * LDC + h * 64;
  size_t rowB0 = (size_t)(b * Tt + qB0r + c16) * LDC + h * 64;
  size_t rowB1 = (size_t)(b * Tt + qB1r + c16) * LDC + h * 64;
  s16x8 qa00 = *(const s16x8*)&Cq[rowA0 + quad * 8];
  s16x8 qa01 = *(const s16x8*)&Cq[rowA0 + 32 + quad * 8];
  s16x8 qa10 = *(const s16x8*)&Cq[rowA1 + quad * 8];
  s16x8 qa11 = *(const s16x8*)&Cq[rowA1 + 32 + quad * 8];
  s16x8 qb00 = *(const s16x8*)&Cq[rowB0 + quad * 8];
  s16x8 qb01 = *(const s16x8*)&Cq[rowB0 + 32 + quad * 8];
  s16x8 qb10 = *(const s16x8*)&Cq[rowB1 + quad * 8];
  s16x8 qb11 = *(const s16x8*)&Cq[rowB1 + 32 + quad * 8];

  float lA0 = 0.f, lA1 = 0.f, lB0 = 0.f, lB1 = 0.f;
  f32x4 oA0[4] = {}, oA1[4] = {}, oB0[4] = {}, oB1[4] = {};

  s16x8 kfX[2][2], kfY[2][2];
  f16x8 vbX[4], vbY[4];

#define LOADT(dstK, dstV, kb) do {                                   \
    const char* Kb_ = Kbase + (size_t)(kb) * 4096;                   \
    const char* Vb_ = Vbase + (size_t)(kb) * 4096;                   \
    dstK[0][0] = *(const s16x8*)(Kb_ + vK0);                         \
    dstK[0][1] = *(const s16x8*)(Kb_ + vK1);                         \
    dstK[1][0] = *(const s16x8*)(Kb_ + 2048 + vK0);                  \
    dstK[1][1] = *(const s16x8*)(Kb_ + 2048 + vK1);                  \
    dstV[0] = *(const f16x8*)(Vb_ + vV);                             \
    dstV[1] = *(const f16x8*)(Vb_ + 1024 + vV);                      \
    dstV[2] = *(const f16x8*)(Vb_ + 2048 + vV);                      \
    dstV[3] = *(const f16x8*)(Vb_ + 3072 + vV);                      \
  } while (0)

#define DOTILES(KF, VF, t) do {                                      \
    int ks_ = (t) * 32;                                              \
    do_tile(ks_, qB0r, quad, c16, qb00, qb01, KF, VF, lB0, oB0);     \
    do_tile(ks_, qB1r, quad, c16, qb10, qb11, KF, VF, lB1, oB1);     \
    if ((t) <= j) {                                                  \
      do_tile(ks_, qA0r, quad, c16, qa00, qa01, KF, VF, lA0, oA0);   \
      do_tile(ks_, qA1r, quad, c16, qa10, qa11, KF, VF, lA1, oA1);   \
    }                                                                \
  } while (0)

  LOADT(kfX, vbX, t0);
  for (int t = t0; t < t1; t += 2) {
    if (t + 1 < t1) LOADT(kfY, vbY, t + 1);
    DOTILES(kfX, vbX, t);
    if (t + 1 < t1) {
      if (t + 2 < t1) LOADT(kfX, vbX, t + 2);
      DOTILES(kfY, vbY, t + 1);
    }
  }
#undef DOTILES
#undef LOADT

  if (kw == 1) {
#pragma unroll
    for (int nt = 0; nt < 4; nt++)
#pragma unroll
      for (int r = 0; r < 4; r++) {
        mrg[lane][nt * 4 + r]      = oB0[nt][r];
        mrg[lane][16 + nt * 4 + r] = oB1[nt][r];
        mrg[lane][32 + nt * 4 + r] = oA0[nt][r];
        mrg[lane][48 + nt * 4 + r] = oA1[nt][r];
      }
    mrg[lane][64] = lB0;
    mrg[lane][65] = lB1;
    mrg[lane][66] = lA0;
    mrg[lane][67] = lA1;
  }
  __syncthreads();
  if (kw == 1) return;
#pragma unroll
  for (int nt = 0; nt < 4; nt++)
#pragma unroll
    for (int r = 0; r < 4; r++) {
      oB0[nt][r] += mrg[lane][nt * 4 + r];
      oB1[nt][r] += mrg[lane][16 + nt * 4 + r];
      oA0[nt][r] += mrg[lane][32 + nt * 4 + r];
      oA1[nt][r] += mrg[lane][48 + nt * 4 + r];
    }
  lB0 += mrg[lane][64];
  lB1 += mrg[lane][65];
  lA0 += mrg[lane][66];
  lA1 += mrg[lane][67];

  lB0 += __shfl_xor(lB0, 16, 64); lB0 += __shfl_xor(lB0, 32, 64);
  lB1 += __shfl_xor(lB1, 16, 64); lB1 += __shfl_xor(lB1, 32, 64);
  lA0 += __shfl_xor(lA0, 16, 64); lA0 += __shfl_xor(lA0, 32, 64);
  lA1 += __shfl_xor(lA1, 16, 64); lA1 += __shfl_xor(lA1, 32, 64);
  float invB0 = 1.f / lB0, invB1 = 1.f / lB1;
  float invA0 = 1.f / lA0, invA1 = 1.f / lA1;
#pragma unroll
  for (int r = 0; r < 4; r++) {
    float ivB0 = __shfl(invB0, quad * 4 + r, 64);
    float ivB1 = __shfl(invB1, quad * 4 + r, 64);
    float ivA0 = __shfl(invA0, quad * 4 + r, 64);
    float ivA1 = __shfl(invA1, quad * 4 + r, 64);
    size_t bB0 = (size_t)(b * Tt + qB0r + quad * 4 + r) * Dd + h * 64;
    size_t bB1 = (size_t)(b * Tt + qB1r + quad * 4 + r) * Dd + h * 64;
    size_t bA0 = (size_t)(b * Tt + qA0r + quad * 4 + r) * Dd + h * 64;
    size_t bA1 = (size_t)(b * Tt + qA1r + quad * 4 + r) * Dd + h * 64;
#pragma unroll
    for (int nt = 0; nt < 4; nt++) {
      po[bB0 + nt * 16 + c16] = f2bf(oB0[nt][r] * ivB0);
      po[bB1 + nt * 16 + c16] = f2bf(oB1[nt][r] * ivB1);
      po[bA0 + nt * 16 + c16] = f2bf(oA0[nt][r] * ivA0);
      po[bA1 + nt * 16 + c16] = f2bf(oA1[nt][r] * ivA1);
    }
  }
}

// scanB with inline cross-chunk prefix:
// B_chunk = sum_{c<chunk} dS^(chunk-1-c) * d * chunkA[c]
// score(t) = d^tl * (u^T B u) + sum_{s<tl} d^(tl-s) (u.w_s)^2

__global__ __launch_bounds__(128) void scanB_kernel(const float* __restrict__ Jw,
                                                    const float* __restrict__ Jr,
                                                    const float* __restrict__ rd,
                                                    const float* __restrict__ chunkA,
                                                    const float* __restrict__ decay_logits,
                                                    float* __restrict__ score_w,
                                                    float* __restrict__ score_r) {
  int blk = blockIdx.x;
  int chunk = blk & 15, bh = (blk >> 4) & 31, type = blk >> 9;
  int tl = threadIdx.x;
  size_t tb = ((size_t)bh * Tt + chunk * 128) * 6;
  const float* U = (type == 0 ? rd : Jw) + tb;
  const float* W = (type == 0 ? Jw : Jr) + tb;
  __shared__ float wv[768];
  __shared__ float Bm[36];
  for (int i = tl; i < 768; i += 128) wv[i] = W[i];
  float d = sigm(decay_logits[bh & 15]);
  if (tl < 36) {
    float dS = powf(d, 128.f);
    float Bv = 0.f;
    size_t base = (size_t)(type * 32 + bh) * 16;
    for (int c = 0; c < chunk; c++)
      Bv = dS * Bv + d * chunkA[(base + c) * 36 + tl];
    Bm[tl] = Bv;
  }
  __syncthreads();
  float u[6];
#pragma unroll
  for (int i = 0; i < 6; i++) u[i] = U[tl * 6 + i];
  float q = 0.f;
#pragma unroll
  for (int i = 0; i < 6; i++) {
    float bi = 0.f;
#pragma unroll
    for (int j = 0; j < 6; j++) bi += Bm[i * 6 + j] * u[j];
    q += u[i] * bi;
  }
  float acc = 0.f;
  for (int s = 0; s < tl; s++) {
    const float* ws = &wv[s * 6];
    float dot = u[0]*ws[0] + u[1]*ws[1] + u[2]*ws[2] + u[3]*ws[3] + u[4]*ws[4] + u[5]*ws[5];
    acc = d * (acc + dot * dot);
  }
  float score = acc + powf(d, (float)tl) * q;
  float* outp = (type == 0 ? score_w : score_r);
  outp[(size_t)bh * Tt + chunk * 128 + tl] = score;
}

// ---------------- gate + combine (2 rows/block, all threads active) ----------

__global__ __launch_bounds__(256) void combine_kernel(const unsigned short* __restrict__ po,
                                                      const unsigned short* __restrict__ Cq,
                                                      const float* __restrict__ score_w,
                                                      const float* __restrict__ score_r,
                                                      const float* __restrict__ mem_scale,
                                                      const float* __restrict__ rw_mix,
                                                      unsigned short* __restrict__ fused) {
  __shared__ float tmp[2][16];
  int half = threadIdx.x >> 7;          // 0/1: which row of the pair
  int tid = threadIdx.x & 127;
  int rowi = blockIdx.x * 2 + half;     // 0..4095
  int b = rowi >> 11, t = rowi & 2047;
  float alpha = sigm(rw_mix[0]);
  if (tid < 16) {
    int h = tid;
    size_t sh = (size_t)(b * 16 + h) * Tt + t;
    float ms = (1.f - alpha) * score_w[sh] + alpha * score_r[sh];
    float gate = sigm(bf2f(Cq[(size_t)rowi * LDC + 3328 + h]));
    tmp[half][h] = sigm(ms * mem_scale[h]) * gate;
  }
  __syncthreads();
  float g = 0.f;
#pragma unroll
  for (int h = 0; h < 16; h++) g += tmp[half][h];
  g *= (1.f / 16.f);
  {
    int c = tid;                        // 8-elem chunk, d = c*8..+8
    int d0 = c * 8;
    s16x8 ov = *(const s16x8*)&po[((size_t)b * Tt + t) * Dd + d0];
    s16x8 mv = *(const s16x8*)&Cq[(size_t)rowi * LDC + 3392 + d0];
    s16x8 out;
#pragma unroll
    for (int e = 0; e < 8; e++)
      out[e] = (short)f2bf(bf2f((unsigned short)ov[e]) + g * bf2f((unsigned short)mv[e]));
    int mt = rowi >> 4, kt = c >> 2, quad = c & 3;
    int lane = (rowi & 15) + quad * 16;
    *(s16x8*)&fused[(((size_t)mt * 32 + kt) * 64 + lane) * 8] = out;
  }
}

// ---------------- launch ----------------

extern "C" void kernel_launch(void* const* d_in, const int* in_sizes, int n_in,
                              void* d_out, int out_size, void* d_ws, size_t ws_size,
                              hipStream_t stream) {
  (void)in_sizes; (void)n_in; (void)out_size; (void)ws_size;
  const float* x         = (const float*)d_in[0];
  const float* qkv_w     = (const float*)d_in[1];
  const float* qkv_b     = (const float*)d_in[2];
  const float* w1w       = (const float*)d_in[3];
  const float* w2w       = (const float*)d_in[4];
  const float* w1r       = (const float*)d_in[5];
  const float* w2r       = (const float*)d_in[6];
  const float* memv_w    = (const float*)d_in[7];
  const float* memv_b    = (const float*)d_in[8];
  const float* memg_w    = (const float*)d_in[9];
  const float* memg_b    = (const float*)d_in[10];
  const float* mem_scale = (const float*)d_in[11];
  const float* rw_mix    = (const float*)d_in[12];
  const float* out_w     = (const float*)d_in[13];
  const float* out_b     = (const float*)d_in[14];
  const float* decay_l   = (const float*)d_in[15];

  char* w = (char*)d_ws;
  unsigned short* xb    = (unsigned short*)(w + 0);          //  8388608  A-frags
  unsigned short* Kt    = (unsigned short*)(w + 0);          //  overlay (xb dead after gemm)
  unsigned short* WT    = (unsigned short*)(w + 8388608);    //  9175040  B-frags (280 nt)
  unsigned short* Vt    = (unsigned short*)(w + 8388608);    //  overlay (WT dead after gemm)
  unsigned short* outT  = (unsigned short*)(w + 17563648);   //  2097152  B-frags (64 nt)
  float*          biasC = (float*)(w + 19660800);            //    17920
  unsigned short* Cbuf  = (unsigned short*)(w + 19678720);   // 36700160
  unsigned short* po    = (unsigned short*)(w + 56378880);   //  8388608
  float*          Jw    = (float*)(w + 73680384);            //  1572864
  float*          Jr    = (float*)(w + 75253248);            //  1572864
  float*          rd    = (float*)(w + 76826112);            //  1572864
  float*          chA   = (float*)(w + 78398976);            //   147456
  float*          sw    = (float*)(w + 78693888);            //   262144
  float*          sr    = (float*)(w + 78956032);            //   262144
  unsigned short* fused = (unsigned short*)(w + 79218176);   //  8388608  A-frags

  prep_kernel<<<3442, 256, 0, stream>>>(x, qkv_w, w1w, w2w, w1r, w2r, memg_w, memv_w,
                                        out_w, qkv_b, memg_b, memv_b,
                                        xb, WT, outT, biasC);

  gemm_wide_kernel<<<576, 512, 0, stream>>>(xb, WT, Cbuf, biasC);

  post1_kernel<<<2304, 256, 0, stream>>>(Cbuf, Kt, Vt, Jw, Jr, rd);
  attn_scanA_kernel<<<2048, 128, 0, stream>>>(Cbuf, Kt, Vt, po, Jw, Jr, decay_l, chA);
  scanB_kernel<<<1024, 128, 0, stream>>>(Jw, Jr, rd, chA, decay_l, sw, sr);
  combine_kernel<<<2048, 256, 0, stream>>>(po, Cbuf, sw, sr, mem_scale, rw_mix, fused);

  gemm_out_kernel<<<512, 256, 0, stream>>>(fused, outT, (float*)d_out, out_b);
}

// Round 15
// 248.612 us; speedup vs baseline: 1.0017x; 1.0017x over previous
//
#include <hip/hip_runtime.h>

#define Bb 2
#define Tt 2048
#define Dd 1024
#define Hh 16
#define LDC 4480

typedef __attribute__((ext_vector_type(8))) short s16x8;
typedef __attribute__((ext_vector_type(4))) float f32x4;
typedef __attribute__((ext_vector_type(8))) _Float16 f16x8;

__device__ __forceinline__ float bf2f(unsigned short u) {
  unsigned v = ((unsigned)u) << 16;
  union { unsigned u; float f; } c; c.u = v; return c.f;
}
__device__ __forceinline__ unsigned short f2bf(float f) {
  union { float f; unsigned u; } c; c.f = f;
  unsigned u = c.u + 0x7fffu + ((c.u >> 16) & 1u);
  return (unsigned short)(u >> 16);
}
__device__ __forceinline__ float sigm(float x) { return 1.f / (1.f + expf(-x)); }

// global -> LDS direct DMA, 16B per lane: lane i's 16B land at ldsbase + i*16.
typedef const __attribute__((address_space(1))) void* gas_ptr;
typedef __attribute__((address_space(3))) void* las_ptr;
__device__ __forceinline__ void gload_lds16(const unsigned short* g, unsigned short* l) {
  __builtin_amdgcn_global_load_lds((gas_ptr)g, (las_ptr)l, 16, 0, 0);
}

// Fragment-major operand layout: frag(t16, kt) holds 64 lanes x 16 B where
// lane = (row&15) + quad*16, bytes = elems [kt*32 + quad*8 .. +8) of row.

// ---------------- fused prep: cast x + build WT + transpose out_w + bias ------
// WT/outT blocks each process 4 kt to amortize per-block staging overhead.
// Grid: 2048 + 1120 + 256 + 18 = 3442.

__global__ __launch_bounds__(256) void prep_kernel(const float* __restrict__ x,
                                                   const float* __restrict__ qkv_w,
                                                   const float* __restrict__ w1w,
                                                   const float* __restrict__ w2w,
                                                   const float* __restrict__ w1r,
                                                   const float* __restrict__ w2r,
                                                   const float* __restrict__ memg_w,
                                                   const float* __restrict__ memv_w,
                                                   const float* __restrict__ out_w,
                                                   const float* __restrict__ qkv_b,
                                                   const float* __restrict__ memg_b,
                                                   const float* __restrict__ memv_b,
                                                   unsigned short* __restrict__ xb,
                                                   unsigned short* __restrict__ WT,
                                                   unsigned short* __restrict__ outT,
                                                   float* __restrict__ biasC) {
  __shared__ float tile[32][33];
  int id = blockIdx.x;
  if (id < 2048) {
    // cast x -> A-fragment-major bf16
    int i = id * 256 + threadIdx.x;     // 16B chunk index
    int row = i >> 7;
    int k8 = i & 127;                    // 8-elem group
    const float4* xv = reinterpret_cast<const float4*>(x + (size_t)i * 8);
    float4 a = xv[0], b = xv[1];
    s16x8 out;
    out[0] = (short)f2bf(a.x); out[1] = (short)f2bf(a.y);
    out[2] = (short)f2bf(a.z); out[3] = (short)f2bf(a.w);
    out[4] = (short)f2bf(b.x); out[5] = (short)f2bf(b.y);
    out[6] = (short)f2bf(b.z); out[7] = (short)f2bf(b.w);
    int mt = row >> 4, kt = k8 >> 2, quad = k8 & 3;
    int lane = (row & 15) + quad * 16;
    *(s16x8*)&xb[(((size_t)mt * 32 + kt) * 64 + lane) * 8] = out;
  } else if (id < 3168) {
    // build WT (concat) -> B-fragment-major; 4 kt per block
    int j = id - 2048;                  // 0..1119
    int n0 = (j % 140) * 32, kt0 = (j / 140) * 4;
    int tx = threadIdx.x & 31, ty = threadIdx.x >> 5;
    for (int kk = 0; kk < 4; kk++) {
      int kt = kt0 + kk, k0 = kt * 32;
#pragma unroll
      for (int i = 0; i < 4; i++) {
        int k = k0 + ty + i * 8, n = n0 + tx;
        float v;
        if (n < 3072)       v = qkv_w[(size_t)k * 3072 + n];
        else if (n < 3136)  v = w1w[k * 64 + (n - 3072)];
        else if (n < 3200)  v = w2w[k * 64 + (n - 3136)];
        else if (n < 3264)  v = w1r[k * 64 + (n - 3200)];
        else if (n < 3328)  v = w2r[k * 64 + (n - 3264)];
        else if (n < 3344)  v = memg_w[k * 16 + (n - 3328)];
        else if (n < 3392)  v = 0.f;
        else if (n < 4416)  v = memv_w[(size_t)k * 1024 + (n - 3392)];
        else                v = 0.f;
        tile[ty + i * 8][tx] = v;
      }
      __syncthreads();
      if (threadIdx.x < 128) {
        int nl = threadIdx.x & 31, quad = threadIdx.x >> 5;
        s16x8 out;
#pragma unroll
        for (int e = 0; e < 8; e++) out[e] = (short)f2bf(tile[quad * 8 + e][nl]);
        int nt = (n0 >> 4) + (nl >> 4);
        int lane = (nl & 15) + quad * 16;
        *(s16x8*)&WT[(((size_t)nt * 32 + kt) * 64 + lane) * 8] = out;
      }
      __syncthreads();   // tile readers done before next kk overwrites
    }
  } else if (id < 3424) {
    // transpose out_w -> B-fragment-major outT; 4 kt per block
    int j = id - 3168;                  // 0..255
    int n0 = (j & 31) * 32, kt0 = (j >> 5) * 4;
    int tx = threadIdx.x & 31, ty = threadIdx.x >> 5;
    for (int kk = 0; kk < 4; kk++) {
      int kt = kt0 + kk, k0 = kt * 32;
#pragma unroll
      for (int i = 0; i < 4; i++) {
        int k = k0 + ty + i * 8, n = n0 + tx;
        tile[ty + i * 8][tx] = out_w[(size_t)k * 1024 + n];
      }
      __syncthreads();
      if (threadIdx.x < 128) {
        int nl = threadIdx.x & 31, quad = threadIdx.x >> 5;
        s16x8 out;
#pragma unroll
        for (int e = 0; e < 8; e++) out[e] = (short)f2bf(tile[quad * 8 + e][nl]);
        int nt = (n0 >> 4) + (nl >> 4);
        int lane = (nl & 15) + quad * 16;
        *(s16x8*)&outT[(((size_t)nt * 32 + kt) * 64 + lane) * 8] = out;
      }
      __syncthreads();
    }
  } else {
    int i = (id - 3424) * 256 + threadIdx.x;
    if (i < LDC) {
      float v = 0.f;
      if (i < 3072) v = qkv_b[i];
      else if (i >= 3328 && i < 3344) v = memg_b[i - 3328];
      else if (i >= 3392 && i < 4416) v = memv_b[i - 3392];
      biasC[i] = v;
    }
  }
}

// ---------------- LDS-staged fragment MFMA GEMM (m97 2-phase structure) -------
// MODE 0: 4096x4480 bf16-out (XCD-partitioned grid, 1152 blocks, 32 dummy)
// Measured 55.1 us; structure plateau confirmed: fragment-direct 55.5,
// 256x128 wide 54.7, 256-tile pipelined 73.5, fat-wave 100.5. Keep 128x128.

template <int MODE>
__global__ __launch_bounds__(256) void gemm_frag_kernel(const unsigned short* __restrict__ Af,
                                                        const unsigned short* __restrict__ Bf,
                                                        void* __restrict__ Cout,
                                                        const float* __restrict__ bias) {
  __shared__ __align__(16) unsigned short lds[2][16][512];  // 2 buf x 16 frags x 1KB = 32KB
  int mTile, nTile;
  if (MODE == 0) {
    const int xx = blockIdx.x & 7, local = blockIdx.x >> 3;
    mTile = (xx >> 1) * 8 + (local & 7);
    nTile = (xx & 1) * 18 + (local >> 3);
    if (nTile >= 35) return;   // uniform whole-block return, before any barrier
  } else {
    mTile = blockIdx.x >> 3;
    nTile = blockIdx.x & 7;
  }
  const int lane = threadIdx.x & 63, wid = threadIdx.x >> 6;
  const int quad = lane >> 4, c16 = lane & 15;
  const int wm = wid >> 1, wn = wid & 1;
  const int mt0 = mTile * 8 + wm * 4;   // global 16-row tile index
  const int nt0 = nTile * 8 + wn * 4;

  // this wave stages frags f = wid*4 .. wid*4+3 (f<8: A tile f, else B tile f-8)
  const unsigned short* src[4];
#pragma unroll
  for (int i = 0; i < 4; i++) {
    int f = wid * 4 + i;
    src[i] = ((f < 8) ? (Af + (size_t)(mTile * 8 + f) * 16384)
                      : (Bf + (size_t)(nTile * 8 + (f - 8)) * 16384))
             + (size_t)lane * 8;
  }

  f32x4 acc[4][4] = {};

#pragma unroll
  for (int i = 0; i < 4; i++) gload_lds16(src[i], &lds[0][wid * 4 + i][0]);
  __syncthreads();

  int buf = 0;
  for (int kt = 0; kt < 32; kt++) {
    if (kt + 1 < 32) {
#pragma unroll
      for (int i = 0; i < 4; i++)
        gload_lds16(src[i] + (size_t)(kt + 1) * 512, &lds[buf ^ 1][wid * 4 + i][0]);
    }
    s16x8 a[4], b[4];
#pragma unroll
    for (int i = 0; i < 4; i++) {
      a[i] = *(const s16x8*)&lds[buf][wm * 4 + i][lane * 8];
      b[i] = *(const s16x8*)&lds[buf][8 + wn * 4 + i][lane * 8];
    }
#pragma unroll
    for (int mt = 0; mt < 4; mt++)
#pragma unroll
      for (int nt = 0; nt < 4; nt++)
        acc[mt][nt] = __builtin_amdgcn_mfma_f32_16x16x32_bf16(a[mt], b[nt],
                                                              acc[mt][nt], 0, 0, 0);
    __syncthreads();
    buf ^= 1;
  }

#pragma unroll
  for (int mt = 0; mt < 4; mt++)
#pragma unroll
    for (int nt = 0; nt < 4; nt++) {
      int col = (nt0 + nt) * 16 + c16;
      float bv = bias[col];
#pragma unroll
      for (int r = 0; r < 4; r++) {
        int row = (mt0 + mt) * 16 + quad * 4 + r;
        if (MODE == 0)
          ((unsigned short*)Cout)[(size_t)row * 4480 + col] = f2bf(acc[mt][nt][r] + bv);
        else
          ((float*)Cout)[(size_t)row * 1024 + col] = acc[mt][nt][r] + bv;
      }
    }
}

// ---------------- output GEMM: 4096x1024 fp32, 128x64 tiles, 512 blocks ------

__global__ __launch_bounds__(256) void gemm_out_kernel(const unsigned short* __restrict__ Af,
                                                       const unsigned short* __restrict__ Bf,
                                                       float* __restrict__ Cout,
                                                       const float* __restrict__ bias) {
  __shared__ __align__(16) unsigned short lds[2][12][512];  // 24 KB
  const int mTile = blockIdx.x >> 4;    // 0..31
  const int nTile = blockIdx.x & 15;    // 0..15
  const int lane = threadIdx.x & 63, wid = threadIdx.x >> 6;
  const int quad = lane >> 4, c16 = lane & 15;
  const int wm = wid >> 1, wn = wid & 1;
  const int mt0 = mTile * 8 + wm * 4;   // 16-row frag index
  const int nt0 = nTile * 4 + wn * 2;   // 16-col frag index

  // 12 frags (8 A + 4 B); wave stages f = wid*3 .. wid*3+2
  const unsigned short* src[3];
#pragma unroll
  for (int i = 0; i < 3; i++) {
    int f = wid * 3 + i;
    src[i] = ((f < 8) ? (Af + (size_t)(mTile * 8 + f) * 16384)
                      : (Bf + (size_t)(nTile * 4 + (f - 8)) * 16384))
             + (size_t)lane * 8;
  }

  f32x4 acc[4][2] = {};

#pragma unroll
  for (int i = 0; i < 3; i++) gload_lds16(src[i], &lds[0][wid * 3 + i][0]);
  __syncthreads();

  int buf = 0;
  for (int kt = 0; kt < 32; kt++) {
    if (kt + 1 < 32) {
#pragma unroll
      for (int i = 0; i < 3; i++)
        gload_lds16(src[i] + (size_t)(kt + 1) * 512, &lds[buf ^ 1][wid * 3 + i][0]);
    }
    s16x8 a[4], b[2];
#pragma unroll
    for (int i = 0; i < 4; i++)
      a[i] = *(const s16x8*)&lds[buf][wm * 4 + i][lane * 8];
#pragma unroll
    for (int j = 0; j < 2; j++)
      b[j] = *(const s16x8*)&lds[buf][8 + wn * 2 + j][lane * 8];
#pragma unroll
    for (int i = 0; i < 4; i++)
#pragma unroll
      for (int j = 0; j < 2; j++)
        acc[i][j] = __builtin_amdgcn_mfma_f32_16x16x32_bf16(a[i], b[j],
                                                            acc[i][j], 0, 0, 0);
    __syncthreads();
    buf ^= 1;
  }

#pragma unroll
  for (int i = 0; i < 4; i++)
#pragma unroll
    for (int j = 0; j < 2; j++) {
      int col = (nt0 + j) * 16 + c16;
      float bv = bias[col];
#pragma unroll
      for (int r = 0; r < 4; r++) {
        int row = (mt0 + i) * 16 + quad * 4 + r;
        Cout[(size_t)row * 1024 + col] = acc[i][j][r] + bv;
      }
    }
}

// ---------------- Plucker helper ----------------

__device__ __forceinline__ void ext6(const float* p, const float* q, float* L) {
  L[0] = p[0] * q[1] - p[1] * q[0];
  L[1] = p[0] * q[2] - p[2] * q[0];
  L[2] = p[0] * q[3] - p[3] * q[0];
  L[3] = p[1] * q[2] - p[2] * q[1];
  L[4] = p[1] * q[3] - p[3] * q[1];
  L[5] = p[2] * q[3] - p[3] * q[2];
  float n = sqrtf(L[0]*L[0] + L[1]*L[1] + L[2]*L[2] + L[3]*L[3] + L[4]*L[4] + L[5]*L[5]);
  float inv = 1.f / fmaxf(n, 1e-12f);
#pragma unroll
  for (int k = 0; k < 6; k++) L[k] *= inv;
}

// ---------------- post1: repack K/V tiles (blocks<2048) + lines (rest) --------
// K is pre-scaled by 0.125 (= DH^-0.5, a power of two, so scores are
// bit-identical to post-scaling) so attn's softmax path skips the multiply.

__global__ __launch_bounds__(256) void post1_kernel(const unsigned short* __restrict__ Cq,
                                                    unsigned short* __restrict__ Kt,
                                                    unsigned short* __restrict__ Vt,
                                                    float* __restrict__ Jw,
                                                    float* __restrict__ Jr,
                                                    float* __restrict__ rd) {
  __shared__ unsigned short vt[32 * 66];
  int id = blockIdx.x;
  int tid = threadIdx.x;
  if (id < 2048) {
    int kb = id & 63, bh = id >> 6;
    int b = bh >> 4, h = bh & 15;
    size_t tbase = ((size_t)bh * 64 + kb) * 2048;
    {
      int key = tid >> 3, p = tid & 7, dg = p ^ (key & 7);
      size_t src = (size_t)(b * Tt + kb * 32 + key) * LDC + 1024 + h * 64 + dg * 8;
      s16x8 kv = *(const s16x8*)&Cq[src];
      s16x8 kvs;
#pragma unroll
      for (int e = 0; e < 8; e++)
        kvs[e] = (short)f2bf(bf2f((unsigned short)kv[e]) * 0.125f);
      *(s16x8*)&Kt[tbase + (size_t)tid * 8] = kvs;
    }
    {
      int row = tid >> 3, c = tid & 7;
      size_t src = (size_t)(b * Tt + kb * 32 + row) * LDC + 2048 + h * 64 + c * 8;
      s16x8 vv = *(const s16x8*)&Cq[src];
#pragma unroll
      for (int e = 0; e < 8; e++) {
        union { _Float16 hf; unsigned short s; } cv;
        cv.hf = (_Float16)bf2f((unsigned short)vv[e]);
        vt[row * 66 + c * 8 + e] = cv.s;
      }
    }
    __syncthreads();
    {
      int d = tid >> 2, p = tid & 3, cq = p ^ ((d >> 2) & 3);
      s16x8 out;
#pragma unroll
      for (int e = 0; e < 8; e++) {
        int key = ((e >> 2) & 1) * 16 + cq * 4 + (e & 3);
        out[e] = (short)vt[key * 66 + d];
      }
      *(s16x8*)&Vt[tbase + (size_t)tid * 8] = out;
    }
  } else {
    int idx = (id - 2048) * 256 + tid;
    int h = idx & 15, t = (idx >> 4) & 2047, b = idx >> 15;
    size_t row = (size_t)(b * Tt + t) * LDC;
    float w1[4], w2[4], r1[4], r2[4];
#pragma unroll
    for (int k = 0; k < 4; k++) {
      w1[k] = (t > 0) ? bf2f(Cq[row - LDC + 3072 + h * 4 + k]) : 0.f;
      w2[k] = bf2f(Cq[row + 3136 + h * 4 + k]);
      r1[k] = bf2f(Cq[row + 3200 + h * 4 + k]);
      r2[k] = bf2f(Cq[row + 3264 + h * 4 + k]);
    }
    float Lw[6], Lr[6];
    ext6(w1, w2, Lw);
    ext6(r1, r2, Lr);
    size_t ob = ((size_t)(b * Hh + h) * Tt + t) * 6;
    Jw[ob + 0] = Lw[5]; Jw[ob + 1] = -Lw[4]; Jw[ob + 2] = Lw[3];
    Jw[ob + 3] = Lw[2]; Jw[ob + 4] = -Lw[1]; Jw[ob + 5] = Lw[0];
    Jr[ob + 0] = Lr[5]; Jr[ob + 1] = -Lr[4]; Jr[ob + 2] = Lr[3];
    Jr[ob + 3] = Lr[2]; Jr[ob + 4] = -Lr[1]; Jr[ob + 5] = Lr[0];
#pragma unroll
    for (int k = 0; k < 6; k++) rd[ob + k] = Lr[k];
  }
}

// ---------------- merged launch: fat-wave attn (blocks 0..1023) + scanA -------
// attn and scanA have no mutual dependency (both read only post1 outputs;
// attn writes po, scanA writes chunkA). One launch saves scanA's serial time
// (its tiny blocks backfill SIMD slots under attn) plus one dispatch gap.

__device__ __forceinline__ void do_tile(int ks, int q0, int quad, int c16,
                                        const s16x8& qf0, const s16x8& qf1,
                                        const s16x8 kf[2][2], const f16x8 vb[4],
                                        float& l_i, f32x4 o[4]) {
  f32x4 st0 = {}, st1 = {};
  __builtin_amdgcn_s_setprio(1);
  st0 = __builtin_amdgcn_mfma_f32_16x16x32_bf16(kf[0][0], qf0, st0, 0, 0, 0);
  st0 = __builtin_amdgcn_mfma_f32_16x16x32_bf16(kf[0][1], qf1, st0, 0, 0, 0);
  st1 = __builtin_amdgcn_mfma_f32_16x16x32_bf16(kf[1][0], qf0, st1, 0, 0, 0);
  st1 = __builtin_amdgcn_mfma_f32_16x16x32_bf16(kf[1][1], qf1, st1, 0, 0, 0);
  __builtin_amdgcn_s_setprio(0);
  bool need_mask = (ks + 31 > q0);
  f16x8 pa;
  float lp = 0.f;
#pragma unroll
  for (int r = 0; r < 4; r++) {
    float v0 = st0[r];     // K pre-scaled by 0.125 in post1
    float v1 = st1[r];
    if (need_mask) {
      v0 = (ks + quad * 4 + r      <= q0 + c16) ? v0 : -1e30f;
      v1 = (ks + 16 + quad * 4 + r <= q0 + c16) ? v1 : -1e30f;
    }
    float p0 = __expf(v0);
    float p1 = __expf(v1);
    lp += p0 + p1;
    pa[r]     = (_Float16)p0;
    pa[4 + r] = (_Float16)p1;
  }
  l_i += lp;
  __builtin_amdgcn_s_setprio(1);
#pragma unroll
  for (int nt = 0; nt < 4; nt++)
    o[nt] = __builtin_amdgcn_mfma_f32_16x16x32_f16(pa, vb[nt], o[nt], 0, 0, 0);
  __builtin_amdgcn_s_setprio(0);
}

__global__ __launch_bounds__(128, 2) void attn_scanA_kernel(const unsigned short* __restrict__ Cq,
                                                            const unsigned short* __restrict__ Kt,
                                                            const unsigned short* __restrict__ Vt,
                                                            unsigned short* __restrict__ po,
                                                            const float* __restrict__ Jw,
                                                            const float* __restrict__ Jr,
                                                            const float* __restrict__ decay_logits,
                                                            float* __restrict__ chunkA) {
  __shared__ float mrg[64][69];   // attn merge buffer
  __shared__ float sv[768];       // scanA staging
  if (blockIdx.x >= 1024) {
    // ---- scanA path (blocks 1024..2047) ----
    int blk = blockIdx.x - 1024;
    int chunk = blk & 15, bh = (blk >> 4) & 31, type = blk >> 9;
    int tid = threadIdx.x;
    const float* V = (type == 0 ? Jw : Jr) + ((size_t)bh * Tt + chunk * 128) * 6;
    for (int i = tid; i < 768; i += 128) sv[i] = V[i];
    __syncthreads();
    float d = sigm(decay_logits[bh & 15]);
    if (tid < 36) {
      int i6 = tid / 6, j6 = tid % 6;
      float A = 0.f;
      for (int s = 0; s < 128; s++) A = d * A + sv[s * 6 + i6] * sv[s * 6 + j6];
      chunkA[((size_t)(type * 32 + bh) * 16 + chunk) * 36 + tid] = A;
    }
    return;
  }
  // ---- attn path (blocks 0..1023) — verified round-12 code ----
  const int id = blockIdx.x;
  const int xcd = id & 7, rest = id >> 3;       // rest 0..127
  const int j = rest & 31;                      // strip-pair 0..31
  const int bh = ((rest >> 5) << 3) | xcd;      // 0..31
  const int b = bh >> 4, h = bh & 15;
  const int kw = threadIdx.x >> 6, lane = threadIdx.x & 63;
  const int quad = lane >> 4, c16 = lane & 15;
  const int qA0r = j * 32,        qA1r = j * 32 + 16;
  const int qB0r = 2016 - j * 32, qB1r = 2032 - j * 32;
  const int Ttot = 64 - j;                      // K-tiles needed (B strips)
  const int ht = (j >= 16) ? 16 : (32 - j);     // balanced split: 64/66 do_tiles
  const int t0 = kw ? ht : 0;
  const int t1 = kw ? Ttot : ht;
  const char* Kbase = (const char*)(Kt + (size_t)bh * 64 * 2048);
  const char* Vbase = (const char*)(Vt + (size_t)bh * 64 * 2048);
  const int vK0 = c16 * 128 + ((quad       ^ (c16 & 7)) * 16);
  const int vK1 = c16 * 128 + (((4 + quad) ^ (c16 & 7)) * 16);
  const int vV  = c16 * 64  + ((quad ^ ((c16 >> 2) & 3)) * 16);

  size_t rowA0 = (size_t)(b * Tt + qA0r + c16) * LDC + h * 64;
  size_t rowA1 = (size_t)(b * Tt + qA1r + c16) * LDC + h * 64;
  size_t rowB0 = (size_t)(b * Tt + qB0r + c16) * LDC + h * 64;
  size_t rowB1 = (size_t)(b * Tt + qB1r + c16) * LDC + h * 64;
  s16x8 qa00 = *(const s16x8*)&Cq[rowA0 + quad * 8];
  s16x8 qa01 = *(const s16x8*)&Cq[rowA0 + 32 + quad * 8];
  s16x8 qa10 = *(const s16x8*)&Cq[rowA1 + quad * 8];
  s16x8 qa11 = *(const s16x8*)&Cq[rowA1 + 32 + quad * 8];
  s16x8 qb00 = *(const s16x8*)&Cq[rowB0 + quad * 8];
  s16x8 qb01 = *(const s16x8*)&Cq[rowB0 + 32 + quad * 8];
  s16x8 qb10 = *(const s16x8*)&Cq[rowB1 + quad * 8];
  s16x8 qb11 = *(const s16x8*)&Cq[rowB1 + 32 + quad * 8];

  float lA0 = 0.f, lA1 = 0.f, lB0 = 0.f, lB1 = 0.f;
  f32x4 oA0[4] = {}, oA1[4] = {}, oB0[4] = {}, oB1[4] = {};

  s16x8 kfX[2][2], kfY[2][2];
  f16x8 vbX[4], vbY[4];

#define LOADT(dstK, dstV, kb) do {                                   \
    const char* Kb_ = Kbase + (size_t)(kb) * 4096;                   \
    const char* Vb_ = Vbase + (size_t)(kb) * 4096;                   \
    dstK[0][0] = *(const s16x8*)(Kb_ + vK0);                         \
    dstK[0][1] = *(const s16x8*)(Kb_ + vK1);                         \
    dstK[1][0] = *(const s16x8*)(Kb_ + 2048 + vK0);                  \
    dstK[1][1] = *(const s16x8*)(Kb_ + 2048 + vK1);                  \
    dstV[0] = *(const f16x8*)(Vb_ + vV);                             \
    dstV[1] = *(const f16x8*)(Vb_ + 1024 + vV);                      \
    dstV[2] = *(const f16x8*)(Vb_ + 2048 + vV);                      \
    dstV[3] = *(const f16x8*)(Vb_ + 3072 + vV);                      \
  } while (0)

#define DOTILES(KF, VF, t) do {                                      \
    int ks_ = (t) * 32;                                              \
    do_tile(ks_, qB0r, quad, c16, qb00, qb01, KF, VF, lB0, oB0);     \
    do_tile(ks_, qB1r, quad, c16, qb10, qb11, KF, VF, lB1, oB1);     \
    if ((t) <= j) {                                                  \
      do_tile(ks_, qA0r, quad, c16, qa00, qa01, KF, VF, lA0, oA0);   \
      do_tile(ks_, qA1r, quad, c16, qa10, qa11, KF, VF, lA1, oA1);   \
    }                                                                \
  } while (0)

  LOADT(kfX, vbX, t0);
  for (int t = t0; t < t1; t += 2) {
    if (t + 1 < t1) LOADT(kfY, vbY, t + 1);
    DOTILES(kfX, vbX, t);
    if (t + 1 < t1) {
      if (t + 2 < t1) LOADT(kfX, vbX, t + 2);
      DOTILES(kfY, vbY, t + 1);
    }
  }
#undef DOTILES
#undef LOADT

  if (kw == 1) {
#pragma unroll
    for (int nt = 0; nt < 4; nt++)
#pragma unroll
      for (int r = 0; r < 4; r++) {
        mrg[lane][nt * 4 + r]      = oB0[nt][r];
        mrg[lane][16 + nt * 4 + r] = oB1[nt][r];
        mrg[lane][32 + nt * 4 + r] = oA0[nt][r];
        mrg[lane][48 + nt * 4 + r] = oA1[nt][r];
      }
    mrg[lane][64] = lB0;
    mrg[lane][65] = lB1;
    mrg[lane][66] = lA0;
    mrg[lane][67] = lA1;
  }
  __syncthreads();
  if (kw == 1) return;
#pragma unroll
  for (int nt = 0; nt < 4; nt++)
#pragma unroll
    for (int r = 0; r < 4; r++) {
      oB0[nt][r] += mrg[lane][nt * 4 + r];
      oB1[nt][r] += mrg[lane][16 + nt * 4 + r];
      oA0[nt][r] += mrg[lane][32 + nt * 4 + r];
      oA1[nt][r] += mrg[lane][48 + nt * 4 + r];
    }
  lB0 += mrg[lane][64];
  lB1 += mrg[lane][65];
  lA0 += mrg[lane][66];
  lA1 += mrg[lane][67];

  lB0 += __shfl_xor(lB0, 16, 64); lB0 += __shfl_xor(lB0, 32, 64);
  lB1 += __shfl_xor(lB1, 16, 64); lB1 += __shfl_xor(lB1, 32, 64);
  lA0 += __shfl_xor(lA0, 16, 64); lA0 += __shfl_xor(lA0, 32, 64);
  lA1 += __shfl_xor(lA1, 16, 64); lA1 += __shfl_xor(lA1, 32, 64);
  float invB0 = 1.f / lB0, invB1 = 1.f / lB1;
  float invA0 = 1.f / lA0, invA1 = 1.f / lA1;
#pragma unroll
  for (int r = 0; r < 4; r++) {
    float ivB0 = __shfl(invB0, quad * 4 + r, 64);
    float ivB1 = __shfl(invB1, quad * 4 + r, 64);
    float ivA0 = __shfl(invA0, quad * 4 + r, 64);
    float ivA1 = __shfl(invA1, quad * 4 + r, 64);
    size_t bB0 = (size_t)(b * Tt + qB0r + quad * 4 + r) * Dd + h * 64;
    size_t bB1 = (size_t)(b * Tt + qB1r + quad * 4 + r) * Dd + h * 64;
    size_t bA0 = (size_t)(b * Tt + qA0r + quad * 4 + r) * Dd + h * 64;
    size_t bA1 = (size_t)(b * Tt + qA1r + quad * 4 + r) * Dd + h * 64;
#pragma unroll
    for (int nt = 0; nt < 4; nt++) {
      po[bB0 + nt * 16 + c16] = f2bf(oB0[nt][r] * ivB0);
      po[bB1 + nt * 16 + c16] = f2bf(oB1[nt][r] * ivB1);
      po[bA0 + nt * 16 + c16] = f2bf(oA0[nt][r] * ivA0);
      po[bA1 + nt * 16 + c16] = f2bf(oA1[nt][r] * ivA1);
    }
  }
}

// scanB with inline cross-chunk prefix:
// B_chunk = sum_{c<chunk} dS^(chunk-1-c) * d * chunkA[c]
// score(t) = d^tl * (u^T B u) + sum_{s<tl} d^(tl-s) (u.w_s)^2

__global__ __launch_bounds__(128) void scanB_kernel(const float* __restrict__ Jw,
                                                    const float* __restrict__ Jr,
                                                    const float* __restrict__ rd,
                                                    const float* __restrict__ chunkA,
                                                    const float* __restrict__ decay_logits,
                                                    float* __restrict__ score_w,
                                                    float* __restrict__ score_r) {
  int blk = blockIdx.x;
  int chunk = blk & 15, bh = (blk >> 4) & 31, type = blk >> 9;
  int tl = threadIdx.x;
  size_t tb = ((size_t)bh * Tt + chunk * 128) * 6;
  const float* U = (type == 0 ? rd : Jw) + tb;
  const float* W = (type == 0 ? Jw : Jr) + tb;
  __shared__ float wv[768];
  __shared__ float Bm[36];
  for (int i = tl; i < 768; i += 128) wv[i] = W[i];
  float d = sigm(decay_logits[bh & 15]);
  if (tl < 36) {
    float dS = powf(d, 128.f);
    float Bv = 0.f;
    size_t base = (size_t)(type * 32 + bh) * 16;
    for (int c = 0; c < chunk; c++)
      Bv = dS * Bv + d * chunkA[(base + c) * 36 + tl];
    Bm[tl] = Bv;
  }
  __syncthreads();
  float u[6];
#pragma unroll
  for (int i = 0; i < 6; i++) u[i] = U[tl * 6 + i];
  float q = 0.f;
#pragma unroll
  for (int i = 0; i < 6; i++) {
    float bi = 0.f;
#pragma unroll
    for (int j = 0; j < 6; j++) bi += Bm[i * 6 + j] * u[j];
    q += u[i] * bi;
  }
  float acc = 0.f;
  for (int s = 0; s < tl; s++) {
    const float* ws = &wv[s * 6];
    float dot = u[0]*ws[0] + u[1]*ws[1] + u[2]*ws[2] + u[3]*ws[3] + u[4]*ws[4] + u[5]*ws[5];
    acc = d * (acc + dot * dot);
  }
  float score = acc + powf(d, (float)tl) * q;
  float* outp = (type == 0 ? score_w : score_r);
  outp[(size_t)bh * Tt + chunk * 128 + tl] = score;
}

// ---------------- gate + combine (2 rows/block, all threads active) ----------

__global__ __launch_bounds__(256) void combine_kernel(const unsigned short* __restrict__ po,
                                                      const unsigned short* __restrict__ Cq,
                                                      const float* __restrict__ score_w,
                                                      const float* __restrict__ score_r,
                                                      const float* __restrict__ mem_scale,
                                                      const float* __restrict__ rw_mix,
                                                      unsigned short* __restrict__ fused) {
  __shared__ float tmp[2][16];
  int half = threadIdx.x >> 7;          // 0/1: which row of the pair
  int tid = threadIdx.x & 127;
  int rowi = blockIdx.x * 2 + half;     // 0..4095
  int b = rowi >> 11, t = rowi & 2047;
  float alpha = sigm(rw_mix[0]);
  if (tid < 16) {
    int h = tid;
    size_t sh = (size_t)(b * 16 + h) * Tt + t;
    float ms = (1.f - alpha) * score_w[sh] + alpha * score_r[sh];
    float gate = sigm(bf2f(Cq[(size_t)rowi * LDC + 3328 + h]));
    tmp[half][h] = sigm(ms * mem_scale[h]) * gate;
  }
  __syncthreads();
  float g = 0.f;
#pragma unroll
  for (int h = 0; h < 16; h++) g += tmp[half][h];
  g *= (1.f / 16.f);
  {
    int c = tid;                        // 8-elem chunk, d = c*8..+8
    int d0 = c * 8;
    s16x8 ov = *(const s16x8*)&po[((size_t)b * Tt + t) * Dd + d0];
    s16x8 mv = *(const s16x8*)&Cq[(size_t)rowi * LDC + 3392 + d0];
    s16x8 out;
#pragma unroll
    for (int e = 0; e < 8; e++)
      out[e] = (short)f2bf(bf2f((unsigned short)ov[e]) + g * bf2f((unsigned short)mv[e]));
    int mt = rowi >> 4, kt = c >> 2, quad = c & 3;
    int lane = (rowi & 15) + quad * 16;
    *(s16x8*)&fused[(((size_t)mt * 32 + kt) * 64 + lane) * 8] = out;
  }
}

// ---------------- launch ----------------

extern "C" void kernel_launch(void* const* d_in, const int* in_sizes, int n_in,
                              void* d_out, int out_size, void* d_ws, size_t ws_size,
                              hipStream_t stream) {
  (void)in_sizes; (void)n_in; (void)out_size; (void)ws_size;
  const float* x         = (const float*)d_in[0];
  const float* qkv_w     = (const float*)d_in[1];
  const float* qkv_b     = (const float*)d_in[2];
  const float* w1w       = (const float*)d_in[3];
  const float* w2w       = (const float*)d_in[4];
  const float* w1r       = (const float*)d_in[5];
  const float* w2r       = (const float*)d_in[6];
  const float* memv_w    = (const float*)d_in[7];
  const float* memv_b    = (const float*)d_in[8];
  const float* memg_w    = (const float*)d_in[9];
  const float* memg_b    = (const float*)d_in[10];
  const float* mem_scale = (const float*)d_in[11];
  const float* rw_mix    = (const float*)d_in[12];
  const float* out_w     = (const float*)d_in[13];
  const float* out_b     = (const float*)d_in[14];
  const float* decay_l   = (const float*)d_in[15];

  char* w = (char*)d_ws;
  unsigned short* xb    = (unsigned short*)(w + 0);          //  8388608  A-frags
  unsigned short* Kt    = (unsigned short*)(w + 0);          //  overlay (xb dead after gemm)
  unsigned short* WT    = (unsigned short*)(w + 8388608);    //  9175040  B-frags (280 nt)
  unsigned short* Vt    = (unsigned short*)(w + 8388608);    //  overlay (WT dead after gemm)
  unsigned short* outT  = (unsigned short*)(w + 17563648);   //  2097152  B-frags (64 nt)
  float*          biasC = (float*)(w + 19660800);            //    17920
  unsigned short* Cbuf  = (unsigned short*)(w + 19678720);   // 36700160
  unsigned short* po    = (unsigned short*)(w + 56378880);   //  8388608
  float*          Jw    = (float*)(w + 73680384);            //  1572864
  float*          Jr    = (float*)(w + 75253248);            //  1572864
  float*          rd    = (float*)(w + 76826112);            //  1572864
  float*          chA   = (float*)(w + 78398976);            //   147456
  float*          sw    = (float*)(w + 78693888);            //   262144
  float*          sr    = (float*)(w + 78956032);            //   262144
  unsigned short* fused = (unsigned short*)(w + 79218176);   //  8388608  A-frags

  prep_kernel<<<3442, 256, 0, stream>>>(x, qkv_w, w1w, w2w, w1r, w2r, memg_w, memv_w,
                                        out_w, qkv_b, memg_b, memv_b,
                                        xb, WT, outT, biasC);

  gemm_frag_kernel<0><<<1152, 256, 0, stream>>>(xb, WT, Cbuf, biasC);

  post1_kernel<<<2304, 256, 0, stream>>>(Cbuf, Kt, Vt, Jw, Jr, rd);
  attn_scanA_kernel<<<2048, 128, 0, stream>>>(Cbuf, Kt, Vt, po, Jw, Jr, decay_l, chA);
  scanB_kernel<<<1024, 128, 0, stream>>>(Jw, Jr, rd, chA, decay_l, sw, sr);
  combine_kernel<<<2048, 256, 0, stream>>>(po, Cbuf, sw, sr, mem_scale, rw_mix, fused);

  gemm_out_kernel<<<512, 256, 0, stream>>>(fused, outT, (float*)d_out, out_b);
}

// Round 16
// 246.749 us; speedup vs baseline: 1.0093x; 1.0076x over previous
//
#include <hip/hip_runtime.h>

#define Bb 2
#define Tt 2048
#define Dd 1024
#define Hh 16
#define LDC 4480

typedef __attribute__((ext_vector_type(8))) short s16x8;
typedef __attribute__((ext_vector_type(4))) float f32x4;
typedef __attribute__((ext_vector_type(8))) _Float16 f16x8;

__device__ __forceinline__ float bf2f(unsigned short u) {
  unsigned v = ((unsigned)u) << 16;
  union { unsigned u; float f; } c; c.u = v; return c.f;
}
__device__ __forceinline__ unsigned short f2bf(float f) {
  union { float f; unsigned u; } c; c.f = f;
  unsigned u = c.u + 0x7fffu + ((c.u >> 16) & 1u);
  return (unsigned short)(u >> 16);
}
__device__ __forceinline__ float sigm(float x) { return 1.f / (1.f + expf(-x)); }

// global -> LDS direct DMA, 16B per lane: lane i's 16B land at ldsbase + i*16.
typedef const __attribute__((address_space(1))) void* gas_ptr;
typedef __attribute__((address_space(3))) void* las_ptr;
__device__ __forceinline__ void gload_lds16(const unsigned short* g, unsigned short* l) {
  __builtin_amdgcn_global_load_lds((gas_ptr)g, (las_ptr)l, 16, 0, 0);
}

// unpack 4 consecutive bf16 (8B, aligned) into f32[4]
__device__ __forceinline__ void bf4_load(const unsigned short* p, float* o) {
  uint2 v = *reinterpret_cast<const uint2*>(p);
  o[0] = bf2f((unsigned short)(v.x & 0xffffu));
  o[1] = bf2f((unsigned short)(v.x >> 16));
  o[2] = bf2f((unsigned short)(v.y & 0xffffu));
  o[3] = bf2f((unsigned short)(v.y >> 16));
}

// Fragment-major operand layout: frag(t16, kt) holds 64 lanes x 16 B where
// lane = (row&15) + quad*16, bytes = elems [kt*32 + quad*8 .. +8) of row.

// ---------------- fused prep: cast x + build WT + transpose out_w + bias ------
// WT/outT blocks each process 4 kt to amortize per-block staging overhead.
// Grid: 2048 + 1120 + 256 + 18 = 3442.

__global__ __launch_bounds__(256) void prep_kernel(const float* __restrict__ x,
                                                   const float* __restrict__ qkv_w,
                                                   const float* __restrict__ w1w,
                                                   const float* __restrict__ w2w,
                                                   const float* __restrict__ w1r,
                                                   const float* __restrict__ w2r,
                                                   const float* __restrict__ memg_w,
                                                   const float* __restrict__ memv_w,
                                                   const float* __restrict__ out_w,
                                                   const float* __restrict__ qkv_b,
                                                   const float* __restrict__ memg_b,
                                                   const float* __restrict__ memv_b,
                                                   unsigned short* __restrict__ xb,
                                                   unsigned short* __restrict__ WT,
                                                   unsigned short* __restrict__ outT,
                                                   float* __restrict__ biasC) {
  __shared__ float tile[32][33];
  int id = blockIdx.x;
  if (id < 2048) {
    // cast x -> A-fragment-major bf16
    int i = id * 256 + threadIdx.x;     // 16B chunk index
    int row = i >> 7;
    int k8 = i & 127;                    // 8-elem group
    const float4* xv = reinterpret_cast<const float4*>(x + (size_t)i * 8);
    float4 a = xv[0], b = xv[1];
    s16x8 out;
    out[0] = (short)f2bf(a.x); out[1] = (short)f2bf(a.y);
    out[2] = (short)f2bf(a.z); out[3] = (short)f2bf(a.w);
    out[4] = (short)f2bf(b.x); out[5] = (short)f2bf(b.y);
    out[6] = (short)f2bf(b.z); out[7] = (short)f2bf(b.w);
    int mt = row >> 4, kt = k8 >> 2, quad = k8 & 3;
    int lane = (row & 15) + quad * 16;
    *(s16x8*)&xb[(((size_t)mt * 32 + kt) * 64 + lane) * 8] = out;
  } else if (id < 3168) {
    // build WT (concat) -> B-fragment-major; 4 kt per block
    int j = id - 2048;                  // 0..1119
    int n0 = (j % 140) * 32, kt0 = (j / 140) * 4;
    int tx = threadIdx.x & 31, ty = threadIdx.x >> 5;
    for (int kk = 0; kk < 4; kk++) {
      int kt = kt0 + kk, k0 = kt * 32;
#pragma unroll
      for (int i = 0; i < 4; i++) {
        int k = k0 + ty + i * 8, n = n0 + tx;
        float v;
        if (n < 3072)       v = qkv_w[(size_t)k * 3072 + n];
        else if (n < 3136)  v = w1w[k * 64 + (n - 3072)];
        else if (n < 3200)  v = w2w[k * 64 + (n - 3136)];
        else if (n < 3264)  v = w1r[k * 64 + (n - 3200)];
        else if (n < 3328)  v = w2r[k * 64 + (n - 3264)];
        else if (n < 3344)  v = memg_w[k * 16 + (n - 3328)];
        else if (n < 3392)  v = 0.f;
        else if (n < 4416)  v = memv_w[(size_t)k * 1024 + (n - 3392)];
        else                v = 0.f;
        tile[ty + i * 8][tx] = v;
      }
      __syncthreads();
      if (threadIdx.x < 128) {
        int nl = threadIdx.x & 31, quad = threadIdx.x >> 5;
        s16x8 out;
#pragma unroll
        for (int e = 0; e < 8; e++) out[e] = (short)f2bf(tile[quad * 8 + e][nl]);
        int nt = (n0 >> 4) + (nl >> 4);
        int lane = (nl & 15) + quad * 16;
        *(s16x8*)&WT[(((size_t)nt * 32 + kt) * 64 + lane) * 8] = out;
      }
      __syncthreads();   // tile readers done before next kk overwrites
    }
  } else if (id < 3424) {
    // transpose out_w -> B-fragment-major outT; 4 kt per block
    int j = id - 3168;                  // 0..255
    int n0 = (j & 31) * 32, kt0 = (j >> 5) * 4;
    int tx = threadIdx.x & 31, ty = threadIdx.x >> 5;
    for (int kk = 0; kk < 4; kk++) {
      int kt = kt0 + kk, k0 = kt * 32;
#pragma unroll
      for (int i = 0; i < 4; i++) {
        int k = k0 + ty + i * 8, n = n0 + tx;
        tile[ty + i * 8][tx] = out_w[(size_t)k * 1024 + n];
      }
      __syncthreads();
      if (threadIdx.x < 128) {
        int nl = threadIdx.x & 31, quad = threadIdx.x >> 5;
        s16x8 out;
#pragma unroll
        for (int e = 0; e < 8; e++) out[e] = (short)f2bf(tile[quad * 8 + e][nl]);
        int nt = (n0 >> 4) + (nl >> 4);
        int lane = (nl & 15) + quad * 16;
        *(s16x8*)&outT[(((size_t)nt * 32 + kt) * 64 + lane) * 8] = out;
      }
      __syncthreads();
    }
  } else {
    int i = (id - 3424) * 256 + threadIdx.x;
    if (i < LDC) {
      float v = 0.f;
      if (i < 3072) v = qkv_b[i];
      else if (i >= 3328 && i < 3344) v = memg_b[i - 3328];
      else if (i >= 3392 && i < 4416) v = memv_b[i - 3392];
      biasC[i] = v;
    }
  }
}

// ---------------- LDS-staged fragment MFMA GEMM (m97 2-phase structure) -------
// MODE 0: 4096x4480 bf16-out (XCD-partitioned grid, 1152 blocks, 32 dummy)
// Measured 55.1 us; structure plateau confirmed: fragment-direct 55.5,
// 256x128 wide 54.7, 256-tile pipelined 73.5, fat-wave 100.5. Keep 128x128.

template <int MODE>
__global__ __launch_bounds__(256) void gemm_frag_kernel(const unsigned short* __restrict__ Af,
                                                        const unsigned short* __restrict__ Bf,
                                                        void* __restrict__ Cout,
                                                        const float* __restrict__ bias) {
  __shared__ __align__(16) unsigned short lds[2][16][512];  // 2 buf x 16 frags x 1KB = 32KB
  int mTile, nTile;
  if (MODE == 0) {
    const int xx = blockIdx.x & 7, local = blockIdx.x >> 3;
    mTile = (xx >> 1) * 8 + (local & 7);
    nTile = (xx & 1) * 18 + (local >> 3);
    if (nTile >= 35) return;   // uniform whole-block return, before any barrier
  } else {
    mTile = blockIdx.x >> 3;
    nTile = blockIdx.x & 7;
  }
  const int lane = threadIdx.x & 63, wid = threadIdx.x >> 6;
  const int quad = lane >> 4, c16 = lane & 15;
  const int wm = wid >> 1, wn = wid & 1;
  const int mt0 = mTile * 8 + wm * 4;   // global 16-row tile index
  const int nt0 = nTile * 8 + wn * 4;

  // this wave stages frags f = wid*4 .. wid*4+3 (f<8: A tile f, else B tile f-8)
  const unsigned short* src[4];
#pragma unroll
  for (int i = 0; i < 4; i++) {
    int f = wid * 4 + i;
    src[i] = ((f < 8) ? (Af + (size_t)(mTile * 8 + f) * 16384)
                      : (Bf + (size_t)(nTile * 8 + (f - 8)) * 16384))
             + (size_t)lane * 8;
  }

  f32x4 acc[4][4] = {};

#pragma unroll
  for (int i = 0; i < 4; i++) gload_lds16(src[i], &lds[0][wid * 4 + i][0]);
  __syncthreads();

  int buf = 0;
  for (int kt = 0; kt < 32; kt++) {
    if (kt + 1 < 32) {
#pragma unroll
      for (int i = 0; i < 4; i++)
        gload_lds16(src[i] + (size_t)(kt + 1) * 512, &lds[buf ^ 1][wid * 4 + i][0]);
    }
    s16x8 a[4], b[4];
#pragma unroll
    for (int i = 0; i < 4; i++) {
      a[i] = *(const s16x8*)&lds[buf][wm * 4 + i][lane * 8];
      b[i] = *(const s16x8*)&lds[buf][8 + wn * 4 + i][lane * 8];
    }
#pragma unroll
    for (int mt = 0; mt < 4; mt++)
#pragma unroll
      for (int nt = 0; nt < 4; nt++)
        acc[mt][nt] = __builtin_amdgcn_mfma_f32_16x16x32_bf16(a[mt], b[nt],
                                                              acc[mt][nt], 0, 0, 0);
    __syncthreads();
    buf ^= 1;
  }

#pragma unroll
  for (int mt = 0; mt < 4; mt++)
#pragma unroll
    for (int nt = 0; nt < 4; nt++) {
      int col = (nt0 + nt) * 16 + c16;
      float bv = bias[col];
#pragma unroll
      for (int r = 0; r < 4; r++) {
        int row = (mt0 + mt) * 16 + quad * 4 + r;
        if (MODE == 0)
          ((unsigned short*)Cout)[(size_t)row * 4480 + col] = f2bf(acc[mt][nt][r] + bv);
        else
          ((float*)Cout)[(size_t)row * 1024 + col] = acc[mt][nt][r] + bv;
      }
    }
}

// ---------------- output GEMM: 4096x1024 fp32, 128x64 tiles, 512 blocks ------

__global__ __launch_bounds__(256) void gemm_out_kernel(const unsigned short* __restrict__ Af,
                                                       const unsigned short* __restrict__ Bf,
                                                       float* __restrict__ Cout,
                                                       const float* __restrict__ bias) {
  __shared__ __align__(16) unsigned short lds[2][12][512];  // 24 KB
  const int mTile = blockIdx.x >> 4;    // 0..31
  const int nTile = blockIdx.x & 15;    // 0..15
  const int lane = threadIdx.x & 63, wid = threadIdx.x >> 6;
  const int quad = lane >> 4, c16 = lane & 15;
  const int wm = wid >> 1, wn = wid & 1;
  const int mt0 = mTile * 8 + wm * 4;   // 16-row frag index
  const int nt0 = nTile * 4 + wn * 2;   // 16-col frag index

  // 12 frags (8 A + 4 B); wave stages f = wid*3 .. wid*3+2
  const unsigned short* src[3];
#pragma unroll
  for (int i = 0; i < 3; i++) {
    int f = wid * 3 + i;
    src[i] = ((f < 8) ? (Af + (size_t)(mTile * 8 + f) * 16384)
                      : (Bf + (size_t)(nTile * 4 + (f - 8)) * 16384))
             + (size_t)lane * 8;
  }

  f32x4 acc[4][2] = {};

#pragma unroll
  for (int i = 0; i < 3; i++) gload_lds16(src[i], &lds[0][wid * 3 + i][0]);
  __syncthreads();

  int buf = 0;
  for (int kt = 0; kt < 32; kt++) {
    if (kt + 1 < 32) {
#pragma unroll
      for (int i = 0; i < 3; i++)
        gload_lds16(src[i] + (size_t)(kt + 1) * 512, &lds[buf ^ 1][wid * 3 + i][0]);
    }
    s16x8 a[4], b[2];
#pragma unroll
    for (int i = 0; i < 4; i++)
      a[i] = *(const s16x8*)&lds[buf][wm * 4 + i][lane * 8];
#pragma unroll
    for (int j = 0; j < 2; j++)
      b[j] = *(const s16x8*)&lds[buf][8 + wn * 2 + j][lane * 8];
#pragma unroll
    for (int i = 0; i < 4; i++)
#pragma unroll
      for (int j = 0; j < 2; j++)
        acc[i][j] = __builtin_amdgcn_mfma_f32_16x16x32_bf16(a[i], b[j],
                                                            acc[i][j], 0, 0, 0);
    __syncthreads();
    buf ^= 1;
  }

#pragma unroll
  for (int i = 0; i < 4; i++)
#pragma unroll
    for (int j = 0; j < 2; j++) {
      int col = (nt0 + j) * 16 + c16;
      float bv = bias[col];
#pragma unroll
      for (int r = 0; r < 4; r++) {
        int row = (mt0 + i) * 16 + quad * 4 + r;
        Cout[(size_t)row * 1024 + col] = acc[i][j][r] + bv;
      }
    }
}

// ---------------- Plucker helper ----------------

__device__ __forceinline__ void ext6(const float* p, const float* q, float* L) {
  L[0] = p[0] * q[1] - p[1] * q[0];
  L[1] = p[0] * q[2] - p[2] * q[0];
  L[2] = p[0] * q[3] - p[3] * q[0];
  L[3] = p[1] * q[2] - p[2] * q[1];
  L[4] = p[1] * q[3] - p[3] * q[1];
  L[5] = p[2] * q[3] - p[3] * q[2];
  float n = sqrtf(L[0]*L[0] + L[1]*L[1] + L[2]*L[2] + L[3]*L[3] + L[4]*L[4] + L[5]*L[5]);
  float inv = 1.f / fmaxf(n, 1e-12f);
#pragma unroll
  for (int k = 0; k < 6; k++) L[k] *= inv;
}

// ---------------- post1: repack K/V tiles (blocks<2048) + lines (rest) --------
// K is pre-scaled by 0.125 (= DH^-0.5, a power of two, so scores are
// bit-identical to post-scaling) so attn's softmax path skips the multiply.
// Lines part: 8B-vector loads (4 bf16 each) + float2 stores (G13).

__global__ __launch_bounds__(256) void post1_kernel(const unsigned short* __restrict__ Cq,
                                                    unsigned short* __restrict__ Kt,
                                                    unsigned short* __restrict__ Vt,
                                                    float* __restrict__ Jw,
                                                    float* __restrict__ Jr,
                                                    float* __restrict__ rd) {
  __shared__ unsigned short vt[32 * 66];
  int id = blockIdx.x;
  int tid = threadIdx.x;
  if (id < 2048) {
    int kb = id & 63, bh = id >> 6;
    int b = bh >> 4, h = bh & 15;
    size_t tbase = ((size_t)bh * 64 + kb) * 2048;
    {
      int key = tid >> 3, p = tid & 7, dg = p ^ (key & 7);
      size_t src = (size_t)(b * Tt + kb * 32 + key) * LDC + 1024 + h * 64 + dg * 8;
      s16x8 kv = *(const s16x8*)&Cq[src];
      s16x8 kvs;
#pragma unroll
      for (int e = 0; e < 8; e++)
        kvs[e] = (short)f2bf(bf2f((unsigned short)kv[e]) * 0.125f);
      *(s16x8*)&Kt[tbase + (size_t)tid * 8] = kvs;
    }
    {
      int row = tid >> 3, c = tid & 7;
      size_t src = (size_t)(b * Tt + kb * 32 + row) * LDC + 2048 + h * 64 + c * 8;
      s16x8 vv = *(const s16x8*)&Cq[src];
#pragma unroll
      for (int e = 0; e < 8; e++) {
        union { _Float16 hf; unsigned short s; } cv;
        cv.hf = (_Float16)bf2f((unsigned short)vv[e]);
        vt[row * 66 + c * 8 + e] = cv.s;
      }
    }
    __syncthreads();
    {
      int d = tid >> 2, p = tid & 3, cq = p ^ ((d >> 2) & 3);
      s16x8 out;
#pragma unroll
      for (int e = 0; e < 8; e++) {
        int key = ((e >> 2) & 1) * 16 + cq * 4 + (e & 3);
        out[e] = (short)vt[key * 66 + d];
      }
      *(s16x8*)&Vt[tbase + (size_t)tid * 8] = out;
    }
  } else {
    int idx = (id - 2048) * 256 + tid;
    int h = idx & 15, t = (idx >> 4) & 2047, b = idx >> 15;
    size_t row = (size_t)(b * Tt + t) * LDC;
    float w1[4], w2[4], r1[4], r2[4];
    if (t > 0) bf4_load(&Cq[row - LDC + 3072 + h * 4], w1);
    else { w1[0] = w1[1] = w1[2] = w1[3] = 0.f; }
    bf4_load(&Cq[row + 3136 + h * 4], w2);
    bf4_load(&Cq[row + 3200 + h * 4], r1);
    bf4_load(&Cq[row + 3264 + h * 4], r2);
    float Lw[6], Lr[6];
    ext6(w1, w2, Lw);
    ext6(r1, r2, Lr);
    size_t ob = ((size_t)(b * Hh + h) * Tt + t) * 6;
    float2* Jw2 = reinterpret_cast<float2*>(&Jw[ob]);
    Jw2[0] = make_float2(Lw[5], -Lw[4]);
    Jw2[1] = make_float2(Lw[3],  Lw[2]);
    Jw2[2] = make_float2(-Lw[1], Lw[0]);
    float2* Jr2 = reinterpret_cast<float2*>(&Jr[ob]);
    Jr2[0] = make_float2(Lr[5], -Lr[4]);
    Jr2[1] = make_float2(Lr[3],  Lr[2]);
    Jr2[2] = make_float2(-Lr[1], Lr[0]);
    float2* rd2 = reinterpret_cast<float2*>(&rd[ob]);
    rd2[0] = make_float2(Lr[0], Lr[1]);
    rd2[1] = make_float2(Lr[2], Lr[3]);
    rd2[2] = make_float2(Lr[4], Lr[5]);
  }
}

// ---------------- merged launch: fat-wave attn (blocks 0..1023) + scanA -------
// attn and scanA have no mutual dependency (both read only post1 outputs;
// attn writes po, scanA writes chunkA). One launch saves scanA's serial time
// (its tiny blocks backfill SIMD slots under attn) plus one dispatch gap.

__device__ __forceinline__ void do_tile(int ks, int q0, int quad, int c16,
                                        const s16x8& qf0, const s16x8& qf1,
                                        const s16x8 kf[2][2], const f16x8 vb[4],
                                        float& l_i, f32x4 o[4]) {
  f32x4 st0 = {}, st1 = {};
  __builtin_amdgcn_s_setprio(1);
  st0 = __builtin_amdgcn_mfma_f32_16x16x32_bf16(kf[0][0], qf0, st0, 0, 0, 0);
  st0 = __builtin_amdgcn_mfma_f32_16x16x32_bf16(kf[0][1], qf1, st0, 0, 0, 0);
  st1 = __builtin_amdgcn_mfma_f32_16x16x32_bf16(kf[1][0], qf0, st1, 0, 0, 0);
  st1 = __builtin_amdgcn_mfma_f32_16x16x32_bf16(kf[1][1], qf1, st1, 0, 0, 0);
  __builtin_amdgcn_s_setprio(0);
  bool need_mask = (ks + 31 > q0);
  f16x8 pa;
  float lp = 0.f;
#pragma unroll
  for (int r = 0; r < 4; r++) {
    float v0 = st0[r];     // K pre-scaled by 0.125 in post1
    float v1 = st1[r];
    if (need_mask) {
      v0 = (ks + quad * 4 + r      <= q0 + c16) ? v0 : -1e30f;
      v1 = (ks + 16 + quad * 4 + r <= q0 + c16) ? v1 : -1e30f;
    }
    float p0 = __expf(v0);
    float p1 = __expf(v1);
    lp += p0 + p1;
    pa[r]     = (_Float16)p0;
    pa[4 + r] = (_Float16)p1;
  }
  l_i += lp;
  __builtin_amdgcn_s_setprio(1);
#pragma unroll
  for (int nt = 0; nt < 4; nt++)
    o[nt] = __builtin_amdgcn_mfma_f32_16x16x32_f16(pa, vb[nt], o[nt], 0, 0, 0);
  __builtin_amdgcn_s_setprio(0);
}

__global__ __launch_bounds__(128, 2) void attn_scanA_kernel(const unsigned short* __restrict__ Cq,
                                                            const unsigned short* __restrict__ Kt,
                                                            const unsigned short* __restrict__ Vt,
                                                            unsigned short* __restrict__ po,
                                                            const float* __restrict__ Jw,
                                                            const float* __restrict__ Jr,
                                                            const float* __restrict__ decay_logits,
                                                            float* __restrict__ chunkA) {
  __shared__ float mrg[64][69];   // attn merge buffer
  __shared__ __align__(16) float sv[768];       // scanA staging
  if (blockIdx.x >= 1024) {
    // ---- scanA path (blocks 1024..2047) ----
    int blk = blockIdx.x - 1024;
    int chunk = blk & 15, bh = (blk >> 4) & 31, type = blk >> 9;
    int tid = threadIdx.x;
    const float* V = (type == 0 ? Jw : Jr) + ((size_t)bh * Tt + chunk * 128) * 6;
    const float4* V4 = reinterpret_cast<const float4*>(V);
    for (int i = tid; i < 192; i += 128) ((float4*)sv)[i] = V4[i];
    __syncthreads();
    float d = sigm(decay_logits[bh & 15]);
    if (tid < 36) {
      int i6 = tid / 6, j6 = tid % 6;
      float A = 0.f;
      for (int s = 0; s < 128; s++) A = d * A + sv[s * 6 + i6] * sv[s * 6 + j6];
      chunkA[((size_t)(type * 32 + bh) * 16 + chunk) * 36 + tid] = A;
    }
    return;
  }
  // ---- attn path (blocks 0..1023) — verified round-12 code ----
  const int id = blockIdx.x;
  const int xcd = id & 7, rest = id >> 3;       // rest 0..127
  const int j = rest & 31;                      // strip-pair 0..31
  const int bh = ((rest >> 5) << 3) | xcd;      // 0..31
  const int b = bh >> 4, h = bh & 15;
  const int kw = threadIdx.x >> 6, lane = threadIdx.x & 63;
  const int quad = lane >> 4, c16 = lane & 15;
  const int qA0r = j * 32,        qA1r = j * 32 + 16;
  const int qB0r = 2016 - j * 32, qB1r = 2032 - j * 32;
  const int Ttot = 64 - j;                      // K-tiles needed (B strips)
  const int ht = (j >= 16) ? 16 : (32 - j);     // balanced split: 64/66 do_tiles
  const int t0 = kw ? ht : 0;
  const int t1 = kw ? Ttot : ht;
  const char* Kbase = (const char*)(Kt + (size_t)bh * 64 * 2048);
  const char* Vbase = (const char*)(Vt + (size_t)bh * 64 * 2048);
  const int vK0 = c16 * 128 + ((quad       ^ (c16 & 7)) * 16);
  const int vK1 = c16 * 128 + (((4 + quad) ^ (c16 & 7)) * 16);
  const int vV  = c16 * 64  + ((quad ^ ((c16 >> 2) & 3)) * 16);

  size_t rowA0 = (size_t)(b * Tt + qA0r + c16) * LDC + h * 64;
  size_t rowA1 = (size_t)(b * Tt + qA1r + c16) * LDC + h * 64;
  size_t rowB0 = (size_t)(b * Tt + qB0r + c16) * LDC + h * 64;
  size_t rowB1 = (size_t)(b * Tt + qB1r + c16) * LDC + h * 64;
  s16x8 qa00 = *(const s16x8*)&Cq[rowA0 + quad * 8];
  s16x8 qa01 = *(const s16x8*)&Cq[rowA0 + 32 + quad * 8];
  s16x8 qa10 = *(const s16x8*)&Cq[rowA1 + quad * 8];
  s16x8 qa11 = *(const s16x8*)&Cq[rowA1 + 32 + quad * 8];
  s16x8 qb00 = *(const s16x8*)&Cq[rowB0 + quad * 8];
  s16x8 qb01 = *(const s16x8*)&Cq[rowB0 + 32 + quad * 8];
  s16x8 qb10 = *(const s16x8*)&Cq[rowB1 + quad * 8];
  s16x8 qb11 = *(const s16x8*)&Cq[rowB1 + 32 + quad * 8];

  float lA0 = 0.f, lA1 = 0.f, lB0 = 0.f, lB1 = 0.f;
  f32x4 oA0[4] = {}, oA1[4] = {}, oB0[4] = {}, oB1[4] = {};

  s16x8 kfX[2][2], kfY[2][2];
  f16x8 vbX[4], vbY[4];

#define LOADT(dstK, dstV, kb) do {                                   \
    const char* Kb_ = Kbase + (size_t)(kb) * 4096;                   \
    const char* Vb_ = Vbase + (size_t)(kb) * 4096;                   \
    dstK[0][0] = *(const s16x8*)(Kb_ + vK0);                         \
    dstK[0][1] = *(const s16x8*)(Kb_ + vK1);                         \
    dstK[1][0] = *(const s16x8*)(Kb_ + 2048 + vK0);                  \
    dstK[1][1] = *(const s16x8*)(Kb_ + 2048 + vK1);                  \
    dstV[0] = *(const f16x8*)(Vb_ + vV);                             \
    dstV[1] = *(const f16x8*)(Vb_ + 1024 + vV);                      \
    dstV[2] = *(const f16x8*)(Vb_ + 2048 + vV);                      \
    dstV[3] = *(const f16x8*)(Vb_ + 3072 + vV);                      \
  } while (0)

#define DOTILES(KF, VF, t) do {                                      \
    int ks_ = (t) * 32;                                              \
    do_tile(ks_, qB0r, quad, c16, qb00, qb01, KF, VF, lB0, oB0);     \
    do_tile(ks_, qB1r, quad, c16, qb10, qb11, KF, VF, lB1, oB1);     \
    if ((t) <= j) {                                                  \
      do_tile(ks_, qA0r, quad, c16, qa00, qa01, KF, VF, lA0, oA0);   \
      do_tile(ks_, qA1r, quad, c16, qa10, qa11, KF, VF, lA1, oA1);   \
    }                                                                \
  } while (0)

  LOADT(kfX, vbX, t0);
  for (int t = t0; t < t1; t += 2) {
    if (t + 1 < t1) LOADT(kfY, vbY, t + 1);
    DOTILES(kfX, vbX, t);
    if (t + 1 < t1) {
      if (t + 2 < t1) LOADT(kfX, vbX, t + 2);
      DOTILES(kfY, vbY, t + 1);
    }
  }
#undef DOTILES
#undef LOADT

  if (kw == 1) {
#pragma unroll
    for (int nt = 0; nt < 4; nt++)
#pragma unroll
      for (int r = 0; r < 4; r++) {
        mrg[lane][nt * 4 + r]      = oB0[nt][r];
        mrg[lane][16 + nt * 4 + r] = oB1[nt][r];
        mrg[lane][32 + nt * 4 + r] = oA0[nt][r];
        mrg[lane][48 + nt * 4 + r] = oA1[nt][r];
      }
    mrg[lane][64] = lB0;
    mrg[lane][65] = lB1;
    mrg[lane][66] = lA0;
    mrg[lane][67] = lA1;
  }
  __syncthreads();
  if (kw == 1) return;
#pragma unroll
  for (int nt = 0; nt < 4; nt++)
#pragma unroll
    for (int r = 0; r < 4; r++) {
      oB0[nt][r] += mrg[lane][nt * 4 + r];
      oB1[nt][r] += mrg[lane][16 + nt * 4 + r];
      oA0[nt][r] += mrg[lane][32 + nt * 4 + r];
      oA1[nt][r] += mrg[lane][48 + nt * 4 + r];
    }
  lB0 += mrg[lane][64];
  lB1 += mrg[lane][65];
  lA0 += mrg[lane][66];
  lA1 += mrg[lane][67];

  lB0 += __shfl_xor(lB0, 16, 64); lB0 += __shfl_xor(lB0, 32, 64);
  lB1 += __shfl_xor(lB1, 16, 64); lB1 += __shfl_xor(lB1, 32, 64);
  lA0 += __shfl_xor(lA0, 16, 64); lA0 += __shfl_xor(lA0, 32, 64);
  lA1 += __shfl_xor(lA1, 16, 64); lA1 += __shfl_xor(lA1, 32, 64);
  float invB0 = 1.f / lB0, invB1 = 1.f / lB1;
  float invA0 = 1.f / lA0, invA1 = 1.f / lA1;
#pragma unroll
  for (int r = 0; r < 4; r++) {
    float ivB0 = __shfl(invB0, quad * 4 + r, 64);
    float ivB1 = __shfl(invB1, quad * 4 + r, 64);
    float ivA0 = __shfl(invA0, quad * 4 + r, 64);
    float ivA1 = __shfl(invA1, quad * 4 + r, 64);
    size_t bB0 = (size_t)(b * Tt + qB0r + quad * 4 + r) * Dd + h * 64;
    size_t bB1 = (size_t)(b * Tt + qB1r + quad * 4 + r) * Dd + h * 64;
    size_t bA0 = (size_t)(b * Tt + qA0r + quad * 4 + r) * Dd + h * 64;
    size_t bA1 = (size_t)(b * Tt + qA1r + quad * 4 + r) * Dd + h * 64;
#pragma unroll
    for (int nt = 0; nt < 4; nt++) {
      po[bB0 + nt * 16 + c16] = f2bf(oB0[nt][r] * ivB0);
      po[bB1 + nt * 16 + c16] = f2bf(oB1[nt][r] * ivB1);
      po[bA0 + nt * 16 + c16] = f2bf(oA0[nt][r] * ivA0);
      po[bA1 + nt * 16 + c16] = f2bf(oA1[nt][r] * ivA1);
    }
  }
}

// scanB with inline cross-chunk prefix:
// B_chunk = sum_{c<chunk} dS^(chunk-1-c) * d * chunkA[c]
// score(t) = d^tl * (u^T B u) + sum_{s<tl} d^(tl-s) (u.w_s)^2
// Staging via float4; u via float2 (G13).

__global__ __launch_bounds__(128) void scanB_kernel(const float* __restrict__ Jw,
                                                    const float* __restrict__ Jr,
                                                    const float* __restrict__ rd,
                                                    const float* __restrict__ chunkA,
                                                    const float* __restrict__ decay_logits,
                                                    float* __restrict__ score_w,
                                                    float* __restrict__ score_r) {
  int blk = blockIdx.x;
  int chunk = blk & 15, bh = (blk >> 4) & 31, type = blk >> 9;
  int tl = threadIdx.x;
  size_t tb = ((size_t)bh * Tt + chunk * 128) * 6;
  const float* U = (type == 0 ? rd : Jw) + tb;
  const float* W = (type == 0 ? Jw : Jr) + tb;
  __shared__ __align__(16) float wv[768];
  __shared__ float Bm[36];
  {
    const float4* W4 = reinterpret_cast<const float4*>(W);
    for (int i = tl; i < 192; i += 128) ((float4*)wv)[i] = W4[i];
  }
  float d = sigm(decay_logits[bh & 15]);
  if (tl < 36) {
    float dS = powf(d, 128.f);
    float Bv = 0.f;
    size_t base = (size_t)(type * 32 + bh) * 16;
    for (int c = 0; c < chunk; c++)
      Bv = dS * Bv + d * chunkA[(base + c) * 36 + tl];
    Bm[tl] = Bv;
  }
  __syncthreads();
  float u[6];
  {
    const float2* U2 = reinterpret_cast<const float2*>(U + (size_t)tl * 6);
    float2 ua = U2[0], ub = U2[1], uc = U2[2];
    u[0] = ua.x; u[1] = ua.y; u[2] = ub.x; u[3] = ub.y; u[4] = uc.x; u[5] = uc.y;
  }
  float q = 0.f;
#pragma unroll
  for (int i = 0; i < 6; i++) {
    float bi = 0.f;
#pragma unroll
    for (int j = 0; j < 6; j++) bi += Bm[i * 6 + j] * u[j];
    q += u[i] * bi;
  }
  float acc = 0.f;
  for (int s = 0; s < tl; s++) {
    const float* ws = &wv[s * 6];
    float dot = u[0]*ws[0] + u[1]*ws[1] + u[2]*ws[2] + u[3]*ws[3] + u[4]*ws[4] + u[5]*ws[5];
    acc = d * (acc + dot * dot);
  }
  float score = acc + powf(d, (float)tl) * q;
  float* outp = (type == 0 ? score_w : score_r);
  outp[(size_t)bh * Tt + chunk * 128 + tl] = score;
}

// ---------------- gate + combine (2 rows/block, all threads active) ----------

__global__ __launch_bounds__(256) void combine_kernel(const unsigned short* __restrict__ po,
                                                      const unsigned short* __restrict__ Cq,
                                                      const float* __restrict__ score_w,
                                                      const float* __restrict__ score_r,
                                                      const float* __restrict__ mem_scale,
                                                      const float* __restrict__ rw_mix,
                                                      unsigned short* __restrict__ fused) {
  __shared__ float tmp[2][16];
  int half = threadIdx.x >> 7;          // 0/1: which row of the pair
  int tid = threadIdx.x & 127;
  int rowi = blockIdx.x * 2 + half;     // 0..4095
  int b = rowi >> 11, t = rowi & 2047;
  float alpha = sigm(rw_mix[0]);
  if (tid < 16) {
    int h = tid;
    size_t sh = (size_t)(b * 16 + h) * Tt + t;
    float ms = (1.f - alpha) * score_w[sh] + alpha * score_r[sh];
    float gate = sigm(bf2f(Cq[(size_t)rowi * LDC + 3328 + h]));
    tmp[half][h] = sigm(ms * mem_scale[h]) * gate;
  }
  __syncthreads();
  float g = 0.f;
#pragma unroll
  for (int h = 0; h < 16; h++) g += tmp[half][h];
  g *= (1.f / 16.f);
  {
    int c = tid;                        // 8-elem chunk, d = c*8..+8
    int d0 = c * 8;
    s16x8 ov = *(const s16x8*)&po[((size_t)b * Tt + t) * Dd + d0];
    s16x8 mv = *(const s16x8*)&Cq[(size_t)rowi * LDC + 3392 + d0];
    s16x8 out;
#pragma unroll
    for (int e = 0; e < 8; e++)
      out[e] = (short)f2bf(bf2f((unsigned short)ov[e]) + g * bf2f((unsigned short)mv[e]));
    int mt = rowi >> 4, kt = c >> 2, quad = c & 3;
    int lane = (rowi & 15) + quad * 16;
    *(s16x8*)&fused[(((size_t)mt * 32 + kt) * 64 + lane) * 8] = out;
  }
}

// ---------------- launch ----------------

extern "C" void kernel_launch(void* const* d_in, const int* in_sizes, int n_in,
                              void* d_out, int out_size, void* d_ws, size_t ws_size,
                              hipStream_t stream) {
  (void)in_sizes; (void)n_in; (void)out_size; (void)ws_size;
  const float* x         = (const float*)d_in[0];
  const float* qkv_w     = (const float*)d_in[1];
  const float* qkv_b     = (const float*)d_in[2];
  const float* w1w       = (const float*)d_in[3];
  const float* w2w       = (const float*)d_in[4];
  const float* w1r       = (const float*)d_in[5];
  const float* w2r       = (const float*)d_in[6];
  const float* memv_w    = (const float*)d_in[7];
  const float* memv_b    = (const float*)d_in[8];
  const float* memg_w    = (const float*)d_in[9];
  const float* memg_b    = (const float*)d_in[10];
  const float* mem_scale = (const float*)d_in[11];
  const float* rw_mix    = (const float*)d_in[12];
  const float* out_w     = (const float*)d_in[13];
  const float* out_b     = (const float*)d_in[14];
  const float* decay_l   = (const float*)d_in[15];

  char* w = (char*)d_ws;
  unsigned short* xb    = (unsigned short*)(w + 0);          //  8388608  A-frags
  unsigned short* Kt    = (unsigned short*)(w + 0);          //  overlay (xb dead after gemm)
  unsigned short* WT    = (unsigned short*)(w + 8388608);    //  9175040  B-frags (280 nt)
  unsigned short* Vt    = (unsigned short*)(w + 8388608);    //  overlay (WT dead after gemm)
  unsigned short* outT  = (unsigned short*)(w + 17563648);   //  2097152  B-frags (64 nt)
  float*          biasC = (float*)(w + 19660800);            //    17920
  unsigned short* Cbuf  = (unsigned short*)(w + 19678720);   // 36700160
  unsigned short* po    = (unsigned short*)(w + 56378880);   //  8388608
  float*          Jw    = (float*)(w + 73680384);            //  1572864
  float*          Jr    = (float*)(w + 75253248);            //  1572864
  float*          rd    = (float*)(w + 76826112);            //  1572864
  float*          chA   = (float*)(w + 78398976);            //   147456
  float*          sw    = (float*)(w + 78693888);            //   262144
  float*          sr    = (float*)(w + 78956032);            //   262144
  unsigned short* fused = (unsigned short*)(w + 79218176);   //  8388608  A-frags

  prep_kernel<<<3442, 256, 0, stream>>>(x, qkv_w, w1w, w2w, w1r, w2r, memg_w, memv_w,
                                        out_w, qkv_b, memg_b, memv_b,
                                        xb, WT, outT, biasC);

  gemm_frag_kernel<0><<<1152, 256, 0, stream>>>(xb, WT, Cbuf, biasC);

  post1_kernel<<<2304, 256, 0, stream>>>(Cbuf, Kt, Vt, Jw, Jr, rd);
  attn_scanA_kernel<<<2048, 128, 0, stream>>>(Cbuf, Kt, Vt, po, Jw, Jr, decay_l, chA);
  scanB_kernel<<<1024, 128, 0, stream>>>(Jw, Jr, rd, chA, decay_l, sw, sr);
  combine_kernel<<<2048, 256, 0, stream>>>(po, Cbuf, sw, sr, mem_scale, rw_mix, fused);

  gemm_out_kernel<<<512, 256, 0, stream>>>(fused, outT, (float*)d_out, out_b);
}